// Round 4
// baseline (377.135 us; speedup 1.0000x reference)
//
#include <hip/hip_runtime.h>
#include <hip/hip_bf16.h>

typedef unsigned short u16;
typedef unsigned int   u32;

using bf8 = __attribute__((ext_vector_type(8))) __bf16;
using f4  = __attribute__((ext_vector_type(4))) float;

__device__ __forceinline__ float b2f(u16 u) {
    union { u32 i; float f; } v; v.i = ((u32)u) << 16; return v.f;
}
__device__ __forceinline__ u16 f2b(float f) {
    union { float f; u32 i; } v; v.f = f;
    u32 x = v.i;
    x += 0x7fffu + ((x >> 16) & 1u);   // RNE
    return (u16)(x >> 16);
}
// Packed fp32x2 -> bf16x2 (low = first arg).
__device__ __forceinline__ u32 pk2(float lo, float hi) {
    union { __hip_bfloat162 h; u32 u; } v;
    v.h = __float22bfloat162_rn(make_float2(lo, hi));
    return v.u;
}

// ---------------------------------------------------------------------------
// Weight swizzle (verified layout — unchanged; frags used as A-operands):
// dst[((kt*16+ct)*64+lane)*8+j] = bf16(W[kt*32+(lane>>4)*8+j][ct*16+(lane&15)])
// ---------------------------------------------------------------------------
__global__ void swz_all(const float* __restrict__ w1, const float* __restrict__ w3,
                        const float* __restrict__ w2, const float* __restrict__ w4,
                        const float* __restrict__ w5, const float* __restrict__ w7,
                        u16* __restrict__ ws) {
    __shared__ u16 slab[32 * 270];
    int b = blockIdx.x, t = threadIdx.x;
    const float* src; u16* dst; int kmax, kt;
    if      (b <  2) { src = w1; dst = ws;          kmax = 54;  kt = b;      }
    else if (b <  4) { src = w3; dst = ws + 16384;  kmax = 54;  kt = b - 2;  }
    else if (b < 12) { src = w2; dst = ws + 32768;  kmax = 256; kt = b - 4;  }
    else if (b < 20) { src = w4; dst = ws + 98304;  kmax = 256; kt = b - 12; }
    else if (b < 28) { src = w5; dst = ws + 163840; kmax = 256; kt = b - 20; }
    else             { src = w7; dst = ws + 229376; kmax = 256; kt = b - 28; }

    #pragma unroll
    for (int it = 0; it < 8; ++it) {
        int flat = it * 1024 + t * 4;
        int row = flat >> 8, col = flat & 255;
        int k = kt * 32 + row;
        float4 v = make_float4(0.f, 0.f, 0.f, 0.f);
        if (k < kmax) v = *(const float4*)(src + k * 256 + col);
        u32* sp = (u32*)&slab[row * 270 + col];
        sp[0] = pk2(v.x, v.y);
        sp[1] = pk2(v.z, v.w);
    }
    __syncthreads();

    int lane = t & 63, wave = t >> 6, lr = lane & 15, kg = lane >> 4;
    #pragma unroll
    for (int i = 0; i < 4; ++i) {
        int ct = wave * 4 + i;
        u16 v[8];
        #pragma unroll
        for (int j = 0; j < 8; ++j)
            v[j] = slab[(kg * 8 + j) * 270 + ct * 16 + lr];
        uint4 o;
        o.x = (u32)v[0] | ((u32)v[1] << 16);
        o.y = (u32)v[2] | ((u32)v[3] << 16);
        o.z = (u32)v[4] | ((u32)v[5] << 16);
        o.w = (u32)v[6] | ((u32)v[7] << 16);
        *(uint4*)(dst + (size_t)(((kt * 16 + ct) * 64 + lane) * 8)) = o;
    }
}

// ---------------------------------------------------------------------------
// Fused critic, operand-swapped MFMA. 512 thr / 8 waves, 2-D wave split:
//   wr = wave>>2 : batch-lane half (rt = 2p+wr -> batch lanes wr*16+lr)
//   wc = wave&3  : 4 hidden column-tiles (ct = wc*4+c)
// Each LDS B-fragment read now feeds 4 MFMAs (was 2) -> b128 traffic
// 1120 -> 608 per WG; pair-sum stays in-register (wave owns all 3 pairs of
// its batch lanes); rho splits nets by wr (wave loads only W5 or W7).
//
// LDS layout (u16), activation rows XOR-swizzled:
//   physical = row*stride + (logical_col ^ ((row&7)<<3))
//   inp: rows 0..95, stride 64  ([0, 6144))
//   h  : rows 0..95, stride 256 ([6144, +24576))
//        S1 rows 0..31, S2 rows 32..63, RH0 rows 64..95, RH1 over S1.
// Total 61440 B -> 2 blocks/CU, 4 waves/SIMD.
// ---------------------------------------------------------------------------
#define H_OFF 6144
#define S2O   (32 * 256)
#define RH0O  (64 * 256)

__global__ __launch_bounds__(512, 4) void critic_kernel(
    const float* __restrict__ obs, const float* __restrict__ ag,
    const float* __restrict__ g,   const float* __restrict__ anchor,
    const float* __restrict__ act,
    const float* __restrict__ b1,  const float* __restrict__ b2,
    const float* __restrict__ b3,  const float* __restrict__ b4,
    const float* __restrict__ b5,  const float* __restrict__ b7,
    const float* __restrict__ w6,  const float* __restrict__ b6,
    const float* __restrict__ w8,  const float* __restrict__ b8,
    const u16* __restrict__ wsz, float* __restrict__ out, int B) {

    __shared__ u16 pool[H_OFF + 96 * 256];   // 30720 u16 = 61440 B

    const int t    = threadIdx.x;
    const int lane = t & 63;
    const int wave = t >> 6;     // 0..7
    const int wr   = wave >> 2;  // 0,1 : batch-lane half / rho net
    const int wc   = wave & 3;   // 0..3: 4 column-tiles
    const int lr   = lane & 15;
    const int lg   = lane >> 4;
    const int wg   = blockIdx.x;
    const int swr  = (lr & 7) << 3;   // row-XOR swizzle (h/inp rows are ..*16+lr)

    // ---- Gather: build pair inputs (96 rows x 54, pad to 64), swizzled.
    // 2 threads/row: part 0 -> cols [0,32), part 1 -> cols [32,64).
    if (t < 192) {
        const int O1[3] = {0, 0, 1}, O2[3] = {1, 2, 2};
        const int JA[3] = {3, 4, 6}, KA[3] = {5, 7, 8};
        int rr = t >> 1, part = t & 1;
        int p = rr >> 5, bl = rr & 31;
        int b = wg * 32 + bl;
        int j = JA[p], k = KA[p];
        bool sel = (anchor[b * 9 + j] - anchor[b * 9 + k]) >= 0.0f;
        u16* row = &pool[rr * 64];
        const int sw = (rr & 7) << 3;
        const u16 ONE = 0x3F80;
        if (part == 0) {
            int bit2 = sel ? j : k;
            int oi = sel ? O1[p] : O2[p];
            row[0 ^ sw] = f2b(ag[b * 9 + p]);
            row[1 ^ sw] = f2b(ag[b * 9 + bit2]);
            row[2 ^ sw] = f2b(g[b * 9 + p]);
            row[3 ^ sw] = f2b(g[b * 9 + bit2]);
            for (int c = 0; c < 10; ++c) row[(4 + c) ^ sw] = f2b(obs[b * 55 + c]);
            row[14 ^ sw] = (oi == 0) ? ONE : 0;
            row[15 ^ sw] = (oi == 1) ? ONE : 0;
            row[16 ^ sw] = (oi == 2) ? ONE : 0;
            for (int c = 0; c < 15; ++c) row[(17 + c) ^ sw] = f2b(obs[b * 55 + 10 + 15 * oi + c]);
        } else {
            int oj = sel ? O2[p] : O1[p];
            row[32 ^ sw] = (oj == 0) ? ONE : 0;
            row[33 ^ sw] = (oj == 1) ? ONE : 0;
            row[34 ^ sw] = (oj == 2) ? ONE : 0;
            for (int c = 0; c < 15; ++c) row[(35 + c) ^ sw] = f2b(obs[b * 55 + 10 + 15 * oj + c]);
            for (int c = 0; c < 4; ++c)  row[(50 + c) ^ sw] = f2b(act[b * 4 + c]);
            for (int c = 54; c < 64; ++c) row[c ^ sw] = 0;
        }
    }
    __syncthreads();

    u32 s1w[4][2];    // net0 pair-sums, packed bf16 pairs (hidden-adjacent)
    u32 s2w[4][2];    // net1 pair-sums

    // ---- Phi networks (net 0: w1/w2, net 1: w3/w4) ----
    for (int net = 0; net < 2; ++net) {
        const u16* Wl1 = wsz + (net ? 16384 : 0);
        const u16* Wl2 = wsz + 32768 + (net ? 65536 : 0);
        const float* bl1 = net ? b3 : b1;
        const float* bl2 = net ? b4 : b2;

        // Layer 1: A=W1^T frags, B=inp rows rt=2p+wr. D=(batch=lr, hid=lg*4+reg)
        f4 acc[3][4];
        #pragma unroll
        for (int p = 0; p < 3; ++p)
            #pragma unroll
            for (int c = 0; c < 4; ++c) acc[p][c] = (f4){0.f, 0.f, 0.f, 0.f};
        __builtin_amdgcn_s_setprio(1);
        #pragma unroll
        for (int kt = 0; kt < 2; ++kt) {
            bf8 wfr[4];
            #pragma unroll
            for (int c = 0; c < 4; ++c)
                wfr[c] = *(const bf8*)(Wl1 + (size_t)(((kt * 16 + wc * 4 + c) * 64 + lane) * 8));
            #pragma unroll
            for (int p = 0; p < 3; ++p) {
                bf8 xfr = *(const bf8*)(&pool[((2 * p + wr) * 16 + lr) * 64 + ((kt * 32 + lg * 8) ^ swr)]);
                #pragma unroll
                for (int c = 0; c < 4; ++c)
                    acc[p][c] = __builtin_amdgcn_mfma_f32_16x16x32_bf16(wfr[c], xfr, acc[p][c], 0, 0, 0);
            }
        }
        __builtin_amdgcn_s_setprio(0);
        #pragma unroll
        for (int c = 0; c < 4; ++c) {
            float4 bv = *(const float4*)(bl1 + (wc * 4 + c) * 16 + lg * 4);
            #pragma unroll
            for (int p = 0; p < 3; ++p) {
                uint2 w;
                w.x = pk2(fmaxf(acc[p][c][0] + bv.x, 0.f), fmaxf(acc[p][c][1] + bv.y, 0.f));
                w.y = pk2(fmaxf(acc[p][c][2] + bv.z, 0.f), fmaxf(acc[p][c][3] + bv.w, 0.f));
                *(uint2*)&pool[H_OFF + ((2 * p + wr) * 16 + lr) * 256 + ((((wc * 4 + c) * 16) + lg * 4) ^ swr)] = w;
            }
        }
        __syncthreads();

        // Layer 2: A=W2^T frags, B=h rows rt=2p+wr. Relu + in-register pair-sum.
        f4 acc2[3][4];
        #pragma unroll
        for (int p = 0; p < 3; ++p)
            #pragma unroll
            for (int c = 0; c < 4; ++c) acc2[p][c] = (f4){0.f, 0.f, 0.f, 0.f};
        __builtin_amdgcn_s_setprio(1);
        #pragma unroll
        for (int ks = 0; ks < 8; ++ks) {
            bf8 wfr[4];
            #pragma unroll
            for (int c = 0; c < 4; ++c)
                wfr[c] = *(const bf8*)(Wl2 + (size_t)(((ks * 16 + wc * 4 + c) * 64 + lane) * 8));
            #pragma unroll
            for (int p = 0; p < 3; ++p) {
                bf8 hfr = *(const bf8*)(&pool[H_OFF + ((2 * p + wr) * 16 + lr) * 256 + ((ks * 32 + lg * 8) ^ swr)]);
                #pragma unroll
                for (int c = 0; c < 4; ++c)
                    acc2[p][c] = __builtin_amdgcn_mfma_f32_16x16x32_bf16(wfr[c], hfr, acc2[p][c], 0, 0, 0);
            }
        }
        __builtin_amdgcn_s_setprio(0);
        #pragma unroll
        for (int c = 0; c < 4; ++c) {
            float4 bv = *(const float4*)(bl2 + (wc * 4 + c) * 16 + lg * 4);
            f4 sv = (f4){0.f, 0.f, 0.f, 0.f};
            #pragma unroll
            for (int p = 0; p < 3; ++p) {
                sv[0] += fmaxf(acc2[p][c][0] + bv.x, 0.f);
                sv[1] += fmaxf(acc2[p][c][1] + bv.y, 0.f);
                sv[2] += fmaxf(acc2[p][c][2] + bv.z, 0.f);
                sv[3] += fmaxf(acc2[p][c][3] + bv.w, 0.f);
            }
            if (net == 0) {
                s1w[c][0] = pk2(sv[0], sv[1]);
                s1w[c][1] = pk2(sv[2], sv[3]);
            } else {
                s2w[c][0] = pk2(sv[0], sv[1]);
                s2w[c][1] = pk2(sv[2], sv[3]);
            }
        }
        __syncthreads();  // h reads done before next net overwrites h
    }

    // ---- Write S1 (rows 0..31), S2 (rows 32..63): one b64 each ----
    #pragma unroll
    for (int c = 0; c < 4; ++c) {
        int base = H_OFF + (wr * 16 + lr) * 256 + ((((wc * 4 + c) * 16) + lg * 4) ^ swr);
        *(uint2*)&pool[base]       = *(uint2*)&s1w[c][0];
        *(uint2*)&pool[base + S2O] = *(uint2*)&s2w[c][0];
    }
    __syncthreads();

    // ---- Rho hidden layer: wr picks the net (wr=0: S1/W5, wr=1: S2/W7) ----
    {
        const u16* Wr  = wsz + (wr ? 229376 : 163840);
        const int soff = wr ? S2O : 0;
        f4 racc[2][4];
        #pragma unroll
        for (int rt = 0; rt < 2; ++rt)
            #pragma unroll
            for (int c = 0; c < 4; ++c) racc[rt][c] = (f4){0.f, 0.f, 0.f, 0.f};
        __builtin_amdgcn_s_setprio(1);
        #pragma unroll
        for (int ks = 0; ks < 8; ++ks) {
            bf8 wf[4];
            #pragma unroll
            for (int c = 0; c < 4; ++c)
                wf[c] = *(const bf8*)(Wr + (size_t)(((ks * 16 + wc * 4 + c) * 64 + lane) * 8));
            #pragma unroll
            for (int rt = 0; rt < 2; ++rt) {
                bf8 sf = *(const bf8*)(&pool[H_OFF + soff + (rt * 16 + lr) * 256 + ((ks * 32 + lg * 8) ^ swr)]);
                #pragma unroll
                for (int c = 0; c < 4; ++c)
                    racc[rt][c] = __builtin_amdgcn_mfma_f32_16x16x32_bf16(wf[c], sf, racc[rt][c], 0, 0, 0);
            }
        }
        __builtin_amdgcn_s_setprio(0);
        // net0 (wr=0) epilogue -> RH0 (rows 64..95; disjoint from S -> no barrier)
        if (wr == 0) {
            #pragma unroll
            for (int c = 0; c < 4; ++c) {
                float4 bv = *(const float4*)(b5 + (wc * 4 + c) * 16 + lg * 4);
                #pragma unroll
                for (int rt = 0; rt < 2; ++rt) {
                    uint2 w;
                    w.x = pk2(fmaxf(racc[rt][c][0] + bv.x, 0.f), fmaxf(racc[rt][c][1] + bv.y, 0.f));
                    w.y = pk2(fmaxf(racc[rt][c][2] + bv.z, 0.f), fmaxf(racc[rt][c][3] + bv.w, 0.f));
                    *(uint2*)&pool[H_OFF + RH0O + (rt * 16 + lr) * 256 + ((((wc * 4 + c) * 16) + lg * 4) ^ swr)] = w;
                }
            }
        }
        __syncthreads();   // all S1 reads done before net1 overwrites it
        // net1 (wr=1) epilogue -> RH1 (over consumed S1, rows 0..31)
        if (wr == 1) {
            #pragma unroll
            for (int c = 0; c < 4; ++c) {
                float4 bv = *(const float4*)(b7 + (wc * 4 + c) * 16 + lg * 4);
                #pragma unroll
                for (int rt = 0; rt < 2; ++rt) {
                    uint2 w;
                    w.x = pk2(fmaxf(racc[rt][c][0] + bv.x, 0.f), fmaxf(racc[rt][c][1] + bv.y, 0.f));
                    w.y = pk2(fmaxf(racc[rt][c][2] + bv.z, 0.f), fmaxf(racc[rt][c][3] + bv.w, 0.f));
                    *(uint2*)&pool[H_OFF + (rt * 16 + lr) * 256 + ((((wc * 4 + c) * 16) + lg * 4) ^ swr)] = w;
                }
            }
        }
        __syncthreads();
    }

    // ---- Final dots, split-K over 8 waves: q = rhoH @ w6 + b6. FP32 OUT ----
    {
        int net = lane >> 5, r = lane & 31;
        int hoff = net ? H_OFF : H_OFF + RH0O;
        const float* wv = net ? w8 : w6;
        const int swq = (r & 7) << 3;
        float s = 0.f;
        #pragma unroll
        for (int it = 0; it < 8; ++it) {
            uint2 two = *(const uint2*)&pool[hoff + r * 256 + ((wave * 32 + it * 4) ^ swq)];
            float4 wq = *(const float4*)(wv + wave * 32 + it * 4);
            s += __uint_as_float(two.x << 16)          * wq.x;
            s += __uint_as_float(two.x & 0xffff0000u)  * wq.y;
            s += __uint_as_float(two.y << 16)          * wq.z;
            s += __uint_as_float(two.y & 0xffff0000u)  * wq.w;
        }
        ((u32*)pool)[t] = __float_as_uint(s);   // partials in dead inp region
    }
    __syncthreads();
    if (t < 64) {
        int net = t >> 5, r = t & 31;
        float qv = net ? b8[0] : b6[0];
        #pragma unroll
        for (int p = 0; p < 8; ++p)
            qv += __uint_as_float(((u32*)pool)[p * 64 + t]);
        out[net * B + wg * 32 + r] = qv;
    }
}

extern "C" void kernel_launch(void* const* d_in, const int* in_sizes, int n_in,
                              void* d_out, int out_size, void* d_ws, size_t ws_size,
                              hipStream_t stream) {
    const float* obs = (const float*)d_in[0];
    const float* ag  = (const float*)d_in[1];
    const float* g   = (const float*)d_in[2];
    const float* anc = (const float*)d_in[3];
    const float* act = (const float*)d_in[4];
    const float* w1  = (const float*)d_in[5];
    const float* b1  = (const float*)d_in[6];
    const float* w2  = (const float*)d_in[7];
    const float* b2  = (const float*)d_in[8];
    const float* w3  = (const float*)d_in[9];
    const float* b3  = (const float*)d_in[10];
    const float* w4  = (const float*)d_in[11];
    const float* b4  = (const float*)d_in[12];
    const float* w5  = (const float*)d_in[13];
    const float* b5  = (const float*)d_in[14];
    const float* w6  = (const float*)d_in[15];
    const float* b6  = (const float*)d_in[16];
    const float* w7  = (const float*)d_in[17];
    const float* b7  = (const float*)d_in[18];
    const float* w8  = (const float*)d_in[19];
    const float* b8  = (const float*)d_in[20];
    u16* ws    = (u16*)d_ws;
    float* out = (float*)d_out;
    int B = in_sizes[0] / 55;

    swz_all<<<36, 256, 0, stream>>>(w1, w3, w2, w4, w5, w7, ws);
    critic_kernel<<<(B + 31) / 32, 512, 0, stream>>>(obs, ag, g, anc, act,
                                                     b1, b2, b3, b4, b5, b7,
                                                     w6, b6, w8, b8, ws, out, B);
}

// Round 8
// 372.164 us; speedup vs baseline: 1.0134x; 1.0134x over previous
//
#include <hip/hip_runtime.h>
#include <hip/hip_bf16.h>

typedef unsigned short u16;
typedef unsigned int   u32;

using bf8 = __attribute__((ext_vector_type(8))) __bf16;
using f4  = __attribute__((ext_vector_type(4))) float;

__device__ __forceinline__ float b2f(u16 u) {
    union { u32 i; float f; } v; v.i = ((u32)u) << 16; return v.f;
}
__device__ __forceinline__ u16 f2b(float f) {
    union { float f; u32 i; } v; v.f = f;
    u32 x = v.i;
    x += 0x7fffu + ((x >> 16) & 1u);   // RNE
    return (u16)(x >> 16);
}
// Packed fp32x2 -> bf16x2 (low = first arg).
__device__ __forceinline__ u32 pk2(float lo, float hi) {
    union { __hip_bfloat162 h; u32 u; } v;
    v.h = __float22bfloat162_rn(make_float2(lo, hi));
    return v.u;
}

// ---------------------------------------------------------------------------
// Weight swizzle (verified layout — unchanged; frags used as A-operands):
// dst[((kt*16+ct)*64+lane)*8+j] = bf16(W[kt*32+(lane>>4)*8+j][ct*16+(lane&15)])
// ---------------------------------------------------------------------------
__global__ void swz_all(const float* __restrict__ w1, const float* __restrict__ w3,
                        const float* __restrict__ w2, const float* __restrict__ w4,
                        const float* __restrict__ w5, const float* __restrict__ w7,
                        u16* __restrict__ ws) {
    __shared__ u16 slab[32 * 270];
    int b = blockIdx.x, t = threadIdx.x;
    const float* src; u16* dst; int kmax, kt;
    if      (b <  2) { src = w1; dst = ws;          kmax = 54;  kt = b;      }
    else if (b <  4) { src = w3; dst = ws + 16384;  kmax = 54;  kt = b - 2;  }
    else if (b < 12) { src = w2; dst = ws + 32768;  kmax = 256; kt = b - 4;  }
    else if (b < 20) { src = w4; dst = ws + 98304;  kmax = 256; kt = b - 12; }
    else if (b < 28) { src = w5; dst = ws + 163840; kmax = 256; kt = b - 20; }
    else             { src = w7; dst = ws + 229376; kmax = 256; kt = b - 28; }

    #pragma unroll
    for (int it = 0; it < 8; ++it) {
        int flat = it * 1024 + t * 4;
        int row = flat >> 8, col = flat & 255;
        int k = kt * 32 + row;
        float4 v = make_float4(0.f, 0.f, 0.f, 0.f);
        if (k < kmax) v = *(const float4*)(src + k * 256 + col);
        u32* sp = (u32*)&slab[row * 270 + col];
        sp[0] = pk2(v.x, v.y);
        sp[1] = pk2(v.z, v.w);
    }
    __syncthreads();

    int lane = t & 63, wave = t >> 6, lr = lane & 15, kg = lane >> 4;
    #pragma unroll
    for (int i = 0; i < 4; ++i) {
        int ct = wave * 4 + i;
        u16 v[8];
        #pragma unroll
        for (int j = 0; j < 8; ++j)
            v[j] = slab[(kg * 8 + j) * 270 + ct * 16 + lr];
        uint4 o;
        o.x = (u32)v[0] | ((u32)v[1] << 16);
        o.y = (u32)v[2] | ((u32)v[3] << 16);
        o.z = (u32)v[4] | ((u32)v[5] << 16);
        o.w = (u32)v[6] | ((u32)v[7] << 16);
        *(uint4*)(dst + (size_t)(((kt * 16 + ct) * 64 + lane) * 8)) = o;
    }
}

// ---------------------------------------------------------------------------
// Fused critic, operand-swapped MFMA. 512 thr / 8 waves, 2-D wave split:
//   wr = wave>>2 : batch-lane half (rt = 2p+wr -> batch lanes wr*16+lr)
//   wc = wave&3  : 4 hidden column-tiles (ct = wc*4+c)
// Each LDS B-fragment read feeds 4 MFMAs -> b128 traffic 1120 -> 608 per WG.
//
// REGALLOC (R4 post-mortem): LDS 61440 B caps occupancy at 2 blocks/CU
// = 4 waves/EU, so <=128 VGPRs is free. __launch_bounds__(512,4) let the
// allocator squeeze to 64 VGPRs -> 300 MB of scratch spill (WRITE_SIZE).
// Pin amdgpu_waves_per_eu(4,4) -> exact 128-VGPR budget, no spill; and
// pre-pack rho accumulators to bf16 words before the barrier (32->16 regs).
//
// LDS layout (u16), activation rows XOR-swizzled:
//   physical = row*stride + (logical_col ^ ((row&7)<<3))
//   inp: rows 0..95, stride 64  ([0, 6144))
//   h  : rows 0..95, stride 256 ([6144, +24576))
//        S1 rows 0..31, S2 rows 32..63, RH0 rows 64..95, RH1 over S1.
// Total 61440 B -> 2 blocks/CU, 4 waves/SIMD.
// ---------------------------------------------------------------------------
#define H_OFF 6144
#define S2O   (32 * 256)
#define RH0O  (64 * 256)

__global__ __launch_bounds__(512) __attribute__((amdgpu_waves_per_eu(4, 4)))
void critic_kernel(
    const float* __restrict__ obs, const float* __restrict__ ag,
    const float* __restrict__ g,   const float* __restrict__ anchor,
    const float* __restrict__ act,
    const float* __restrict__ b1,  const float* __restrict__ b2,
    const float* __restrict__ b3,  const float* __restrict__ b4,
    const float* __restrict__ b5,  const float* __restrict__ b7,
    const float* __restrict__ w6,  const float* __restrict__ b6,
    const float* __restrict__ w8,  const float* __restrict__ b8,
    const u16* __restrict__ wsz, float* __restrict__ out, int B) {

    __shared__ u16 pool[H_OFF + 96 * 256];   // 30720 u16 = 61440 B

    const int t    = threadIdx.x;
    const int lane = t & 63;
    const int wave = t >> 6;     // 0..7
    const int wr   = wave >> 2;  // 0,1 : batch-lane half / rho net
    const int wc   = wave & 3;   // 0..3: 4 column-tiles
    const int lr   = lane & 15;
    const int lg   = lane >> 4;
    const int wg   = blockIdx.x;
    const int swr  = (lr & 7) << 3;   // row-XOR swizzle (h/inp rows are ..*16+lr)

    // ---- Gather: build pair inputs (96 rows x 54, pad to 64), swizzled.
    // 2 threads/row: part 0 -> cols [0,32), part 1 -> cols [32,64).
    if (t < 192) {
        const int O1[3] = {0, 0, 1}, O2[3] = {1, 2, 2};
        const int JA[3] = {3, 4, 6}, KA[3] = {5, 7, 8};
        int rr = t >> 1, part = t & 1;
        int p = rr >> 5, bl = rr & 31;
        int b = wg * 32 + bl;
        int j = JA[p], k = KA[p];
        bool sel = (anchor[b * 9 + j] - anchor[b * 9 + k]) >= 0.0f;
        u16* row = &pool[rr * 64];
        const int sw = (rr & 7) << 3;
        const u16 ONE = 0x3F80;
        if (part == 0) {
            int bit2 = sel ? j : k;
            int oi = sel ? O1[p] : O2[p];
            row[0 ^ sw] = f2b(ag[b * 9 + p]);
            row[1 ^ sw] = f2b(ag[b * 9 + bit2]);
            row[2 ^ sw] = f2b(g[b * 9 + p]);
            row[3 ^ sw] = f2b(g[b * 9 + bit2]);
            for (int c = 0; c < 10; ++c) row[(4 + c) ^ sw] = f2b(obs[b * 55 + c]);
            row[14 ^ sw] = (oi == 0) ? ONE : 0;
            row[15 ^ sw] = (oi == 1) ? ONE : 0;
            row[16 ^ sw] = (oi == 2) ? ONE : 0;
            for (int c = 0; c < 15; ++c) row[(17 + c) ^ sw] = f2b(obs[b * 55 + 10 + 15 * oi + c]);
        } else {
            int oj = sel ? O2[p] : O1[p];
            row[32 ^ sw] = (oj == 0) ? ONE : 0;
            row[33 ^ sw] = (oj == 1) ? ONE : 0;
            row[34 ^ sw] = (oj == 2) ? ONE : 0;
            for (int c = 0; c < 15; ++c) row[(35 + c) ^ sw] = f2b(obs[b * 55 + 10 + 15 * oj + c]);
            for (int c = 0; c < 4; ++c)  row[(50 + c) ^ sw] = f2b(act[b * 4 + c]);
            for (int c = 54; c < 64; ++c) row[c ^ sw] = 0;
        }
    }
    __syncthreads();

    u32 s1w[4][2];    // net0 pair-sums, packed bf16 pairs (hidden-adjacent)
    u32 s2w[4][2];    // net1 pair-sums

    // ---- Phi networks (net 0: w1/w2, net 1: w3/w4) ----
    for (int net = 0; net < 2; ++net) {
        const u16* Wl1 = wsz + (net ? 16384 : 0);
        const u16* Wl2 = wsz + 32768 + (net ? 65536 : 0);
        const float* bl1 = net ? b3 : b1;
        const float* bl2 = net ? b4 : b2;

        // Layer 1: A=W1^T frags, B=inp rows rt=2p+wr. D=(batch=lr, hid=lg*4+reg)
        f4 acc[3][4];
        #pragma unroll
        for (int p = 0; p < 3; ++p)
            #pragma unroll
            for (int c = 0; c < 4; ++c) acc[p][c] = (f4){0.f, 0.f, 0.f, 0.f};
        __builtin_amdgcn_s_setprio(1);
        #pragma unroll
        for (int kt = 0; kt < 2; ++kt) {
            bf8 wfr[4];
            #pragma unroll
            for (int c = 0; c < 4; ++c)
                wfr[c] = *(const bf8*)(Wl1 + (size_t)(((kt * 16 + wc * 4 + c) * 64 + lane) * 8));
            #pragma unroll
            for (int p = 0; p < 3; ++p) {
                bf8 xfr = *(const bf8*)(&pool[((2 * p + wr) * 16 + lr) * 64 + ((kt * 32 + lg * 8) ^ swr)]);
                #pragma unroll
                for (int c = 0; c < 4; ++c)
                    acc[p][c] = __builtin_amdgcn_mfma_f32_16x16x32_bf16(wfr[c], xfr, acc[p][c], 0, 0, 0);
            }
        }
        __builtin_amdgcn_s_setprio(0);
        #pragma unroll
        for (int c = 0; c < 4; ++c) {
            float4 bv = *(const float4*)(bl1 + (wc * 4 + c) * 16 + lg * 4);
            #pragma unroll
            for (int p = 0; p < 3; ++p) {
                uint2 w;
                w.x = pk2(fmaxf(acc[p][c][0] + bv.x, 0.f), fmaxf(acc[p][c][1] + bv.y, 0.f));
                w.y = pk2(fmaxf(acc[p][c][2] + bv.z, 0.f), fmaxf(acc[p][c][3] + bv.w, 0.f));
                *(uint2*)&pool[H_OFF + ((2 * p + wr) * 16 + lr) * 256 + ((((wc * 4 + c) * 16) + lg * 4) ^ swr)] = w;
            }
        }
        __syncthreads();

        // Layer 2: A=W2^T frags, B=h rows rt=2p+wr. Relu + in-register pair-sum.
        f4 acc2[3][4];
        #pragma unroll
        for (int p = 0; p < 3; ++p)
            #pragma unroll
            for (int c = 0; c < 4; ++c) acc2[p][c] = (f4){0.f, 0.f, 0.f, 0.f};
        __builtin_amdgcn_s_setprio(1);
        #pragma unroll
        for (int ks = 0; ks < 8; ++ks) {
            bf8 wfr[4];
            #pragma unroll
            for (int c = 0; c < 4; ++c)
                wfr[c] = *(const bf8*)(Wl2 + (size_t)(((ks * 16 + wc * 4 + c) * 64 + lane) * 8));
            #pragma unroll
            for (int p = 0; p < 3; ++p) {
                bf8 hfr = *(const bf8*)(&pool[H_OFF + ((2 * p + wr) * 16 + lr) * 256 + ((ks * 32 + lg * 8) ^ swr)]);
                #pragma unroll
                for (int c = 0; c < 4; ++c)
                    acc2[p][c] = __builtin_amdgcn_mfma_f32_16x16x32_bf16(wfr[c], hfr, acc2[p][c], 0, 0, 0);
            }
        }
        __builtin_amdgcn_s_setprio(0);
        #pragma unroll
        for (int c = 0; c < 4; ++c) {
            float4 bv = *(const float4*)(bl2 + (wc * 4 + c) * 16 + lg * 4);
            f4 sv = (f4){0.f, 0.f, 0.f, 0.f};
            #pragma unroll
            for (int p = 0; p < 3; ++p) {
                sv[0] += fmaxf(acc2[p][c][0] + bv.x, 0.f);
                sv[1] += fmaxf(acc2[p][c][1] + bv.y, 0.f);
                sv[2] += fmaxf(acc2[p][c][2] + bv.z, 0.f);
                sv[3] += fmaxf(acc2[p][c][3] + bv.w, 0.f);
            }
            if (net == 0) {
                s1w[c][0] = pk2(sv[0], sv[1]);
                s1w[c][1] = pk2(sv[2], sv[3]);
            } else {
                s2w[c][0] = pk2(sv[0], sv[1]);
                s2w[c][1] = pk2(sv[2], sv[3]);
            }
        }
        __syncthreads();  // h reads done before next net overwrites h
    }

    // ---- Write S1 (rows 0..31), S2 (rows 32..63): one b64 each ----
    #pragma unroll
    for (int c = 0; c < 4; ++c) {
        int base = H_OFF + (wr * 16 + lr) * 256 + ((((wc * 4 + c) * 16) + lg * 4) ^ swr);
        *(uint2*)&pool[base]       = *(uint2*)&s1w[c][0];
        *(uint2*)&pool[base + S2O] = *(uint2*)&s2w[c][0];
    }
    __syncthreads();

    // ---- Rho hidden layer: wr picks the net (wr=0: S1/W5, wr=1: S2/W7) ----
    {
        const u16* Wr   = wsz + (wr ? 229376 : 163840);
        const int soff  = wr ? S2O : 0;
        const float* br = wr ? b7 : b5;
        f4 racc[2][4];
        #pragma unroll
        for (int rt = 0; rt < 2; ++rt)
            #pragma unroll
            for (int c = 0; c < 4; ++c) racc[rt][c] = (f4){0.f, 0.f, 0.f, 0.f};
        __builtin_amdgcn_s_setprio(1);
        #pragma unroll
        for (int ks = 0; ks < 8; ++ks) {
            bf8 wf[4];
            #pragma unroll
            for (int c = 0; c < 4; ++c)
                wf[c] = *(const bf8*)(Wr + (size_t)(((ks * 16 + wc * 4 + c) * 64 + lane) * 8));
            #pragma unroll
            for (int rt = 0; rt < 2; ++rt) {
                bf8 sf = *(const bf8*)(&pool[H_OFF + soff + (rt * 16 + lr) * 256 + ((ks * 32 + lg * 8) ^ swr)]);
                #pragma unroll
                for (int c = 0; c < 4; ++c)
                    racc[rt][c] = __builtin_amdgcn_mfma_f32_16x16x32_bf16(wf[c], sf, racc[rt][c], 0, 0, 0);
            }
        }
        __builtin_amdgcn_s_setprio(0);
        // Pack bias+relu+bf16 BEFORE the barrier: 32 f32 -> 16 u32 live regs.
        uint2 rw[2][4];
        #pragma unroll
        for (int c = 0; c < 4; ++c) {
            float4 bv = *(const float4*)(br + (wc * 4 + c) * 16 + lg * 4);
            #pragma unroll
            for (int rt = 0; rt < 2; ++rt) {
                rw[rt][c].x = pk2(fmaxf(racc[rt][c][0] + bv.x, 0.f), fmaxf(racc[rt][c][1] + bv.y, 0.f));
                rw[rt][c].y = pk2(fmaxf(racc[rt][c][2] + bv.z, 0.f), fmaxf(racc[rt][c][3] + bv.w, 0.f));
            }
        }
        // net0 (wr=0) -> RH0 (rows 64..95; disjoint from S reads -> no barrier)
        if (wr == 0) {
            #pragma unroll
            for (int c = 0; c < 4; ++c)
                #pragma unroll
                for (int rt = 0; rt < 2; ++rt)
                    *(uint2*)&pool[H_OFF + RH0O + (rt * 16 + lr) * 256 + ((((wc * 4 + c) * 16) + lg * 4) ^ swr)] = rw[rt][c];
        }
        __syncthreads();   // all S1 reads done before net1 overwrites it
        // net1 (wr=1) -> RH1 (over consumed S1, rows 0..31)
        if (wr == 1) {
            #pragma unroll
            for (int c = 0; c < 4; ++c)
                #pragma unroll
                for (int rt = 0; rt < 2; ++rt)
                    *(uint2*)&pool[H_OFF + (rt * 16 + lr) * 256 + ((((wc * 4 + c) * 16) + lg * 4) ^ swr)] = rw[rt][c];
        }
        __syncthreads();
    }

    // ---- Final dots, split-K over 8 waves: q = rhoH @ w6 + b6. FP32 OUT ----
    {
        int net = lane >> 5, r = lane & 31;
        int hoff = net ? H_OFF : H_OFF + RH0O;
        const float* wv = net ? w8 : w6;
        const int swq = (r & 7) << 3;
        float s = 0.f;
        #pragma unroll
        for (int it = 0; it < 8; ++it) {
            uint2 two = *(const uint2*)&pool[hoff + r * 256 + ((wave * 32 + it * 4) ^ swq)];
            float4 wq = *(const float4*)(wv + wave * 32 + it * 4);
            s += __uint_as_float(two.x << 16)          * wq.x;
            s += __uint_as_float(two.x & 0xffff0000u)  * wq.y;
            s += __uint_as_float(two.y << 16)          * wq.z;
            s += __uint_as_float(two.y & 0xffff0000u)  * wq.w;
        }
        ((u32*)pool)[t] = __float_as_uint(s);   // partials in dead inp region
    }
    __syncthreads();
    if (t < 64) {
        int net = t >> 5, r = t & 31;
        float qv = net ? b8[0] : b6[0];
        #pragma unroll
        for (int p = 0; p < 8; ++p)
            qv += __uint_as_float(((u32*)pool)[p * 64 + t]);
        out[net * B + wg * 32 + r] = qv;
    }
}

extern "C" void kernel_launch(void* const* d_in, const int* in_sizes, int n_in,
                              void* d_out, int out_size, void* d_ws, size_t ws_size,
                              hipStream_t stream) {
    const float* obs = (const float*)d_in[0];
    const float* ag  = (const float*)d_in[1];
    const float* g   = (const float*)d_in[2];
    const float* anc = (const float*)d_in[3];
    const float* act = (const float*)d_in[4];
    const float* w1  = (const float*)d_in[5];
    const float* b1  = (const float*)d_in[6];
    const float* w2  = (const float*)d_in[7];
    const float* b2  = (const float*)d_in[8];
    const float* w3  = (const float*)d_in[9];
    const float* b3  = (const float*)d_in[10];
    const float* w4  = (const float*)d_in[11];
    const float* b4  = (const float*)d_in[12];
    const float* w5  = (const float*)d_in[13];
    const float* b5  = (const float*)d_in[14];
    const float* w6  = (const float*)d_in[15];
    const float* b6  = (const float*)d_in[16];
    const float* w7  = (const float*)d_in[17];
    const float* b7  = (const float*)d_in[18];
    const float* w8  = (const float*)d_in[19];
    const float* b8  = (const float*)d_in[20];
    u16* ws    = (u16*)d_ws;
    float* out = (float*)d_out;
    int B = in_sizes[0] / 55;

    swz_all<<<36, 256, 0, stream>>>(w1, w3, w2, w4, w5, w7, ws);
    critic_kernel<<<(B + 31) / 32, 512, 0, stream>>>(obs, ag, g, anc, act,
                                                     b1, b2, b3, b4, b5, b7,
                                                     w6, b6, w8, b8, ws, out, B);
}

// Round 9
// 212.168 us; speedup vs baseline: 1.7775x; 1.7541x over previous
//
#include <hip/hip_runtime.h>
#include <hip/hip_bf16.h>

typedef unsigned short u16;
typedef unsigned int   u32;

using bf8 = __attribute__((ext_vector_type(8))) __bf16;
using f4  = __attribute__((ext_vector_type(4))) float;

__device__ __forceinline__ float b2f(u16 u) {
    union { u32 i; float f; } v; v.i = ((u32)u) << 16; return v.f;
}
__device__ __forceinline__ u16 f2b(float f) {
    union { float f; u32 i; } v; v.f = f;
    u32 x = v.i;
    x += 0x7fffu + ((x >> 16) & 1u);   // RNE
    return (u16)(x >> 16);
}
// Packed fp32x2 -> bf16x2 (low = first arg).
__device__ __forceinline__ u32 pk2(float lo, float hi) {
    union { __hip_bfloat162 h; u32 u; } v;
    v.h = __float22bfloat162_rn(make_float2(lo, hi));
    return v.u;
}

// ---------------------------------------------------------------------------
// Weight swizzle (verified layout — unchanged; frags used as A-operands):
// dst[((kt*16+ct)*64+lane)*8+j] = bf16(W[kt*32+(lane>>4)*8+j][ct*16+(lane&15)])
// ---------------------------------------------------------------------------
__global__ void swz_all(const float* __restrict__ w1, const float* __restrict__ w3,
                        const float* __restrict__ w2, const float* __restrict__ w4,
                        const float* __restrict__ w5, const float* __restrict__ w7,
                        u16* __restrict__ ws) {
    __shared__ u16 slab[32 * 270];
    int b = blockIdx.x, t = threadIdx.x;
    const float* src; u16* dst; int kmax, kt;
    if      (b <  2) { src = w1; dst = ws;          kmax = 54;  kt = b;      }
    else if (b <  4) { src = w3; dst = ws + 16384;  kmax = 54;  kt = b - 2;  }
    else if (b < 12) { src = w2; dst = ws + 32768;  kmax = 256; kt = b - 4;  }
    else if (b < 20) { src = w4; dst = ws + 98304;  kmax = 256; kt = b - 12; }
    else if (b < 28) { src = w5; dst = ws + 163840; kmax = 256; kt = b - 20; }
    else             { src = w7; dst = ws + 229376; kmax = 256; kt = b - 28; }

    #pragma unroll
    for (int it = 0; it < 8; ++it) {
        int flat = it * 1024 + t * 4;
        int row = flat >> 8, col = flat & 255;
        int k = kt * 32 + row;
        float4 v = make_float4(0.f, 0.f, 0.f, 0.f);
        if (k < kmax) v = *(const float4*)(src + k * 256 + col);
        u32* sp = (u32*)&slab[row * 270 + col];
        sp[0] = pk2(v.x, v.y);
        sp[1] = pk2(v.z, v.w);
    }
    __syncthreads();

    int lane = t & 63, wave = t >> 6, lr = lane & 15, kg = lane >> 4;
    #pragma unroll
    for (int i = 0; i < 4; ++i) {
        int ct = wave * 4 + i;
        u16 v[8];
        #pragma unroll
        for (int j = 0; j < 8; ++j)
            v[j] = slab[(kg * 8 + j) * 270 + ct * 16 + lr];
        uint4 o;
        o.x = (u32)v[0] | ((u32)v[1] << 16);
        o.y = (u32)v[2] | ((u32)v[3] << 16);
        o.z = (u32)v[4] | ((u32)v[5] << 16);
        o.w = (u32)v[6] | ((u32)v[7] << 16);
        *(uint4*)(dst + (size_t)(((kt * 16 + ct) * 64 + lane) * 8)) = o;
    }
}

// ---------------------------------------------------------------------------
// Fused critic, operand-swapped MFMA. 512 thr / 8 waves, 2-D wave split:
//   wr = wave>>2 : batch-lane half (rt = 2p+wr -> batch lanes wr*16+lr)
//   wc = wave&3  : 4 hidden column-tiles (ct = wc*4+c)
// Each LDS B-fragment read feeds 4 MFMAs -> b128 traffic 1120 -> 608 per WG.
//
// REGALLOC (R8 post-mortem): waves_per_eu(4,4) and launch_bounds(512,4)
// compile IDENTICALLY (both = 128-VGPR budget) and both spill 300 MB.
// Root cause: full #pragma unroll on the ks loops lets the compiler hoist
// ALL W-frag loads (8 ks x wfr[4] = 128 VGPRs in flight) -> peak pressure
// ~200 > 128. Fix: #pragma unroll 2 on L2/rho ks loops caps in-flight
// frag loads at 32 VGPRs -> peak ~110 < 128, no spill. 24 MFMAs per
// partial-unroll iteration still hide the L2-resident weight-load latency.
//
// LDS layout (u16), activation rows XOR-swizzled:
//   physical = row*stride + (logical_col ^ ((row&7)<<3))
//   inp: rows 0..95, stride 64  ([0, 6144))
//   h  : rows 0..95, stride 256 ([6144, +24576))
//        S1 rows 0..31, S2 rows 32..63, RH0 rows 64..95, RH1 over S1.
// Total 61440 B -> 2 blocks/CU, 4 waves/SIMD.
// ---------------------------------------------------------------------------
#define H_OFF 6144
#define S2O   (32 * 256)
#define RH0O  (64 * 256)

__global__ __launch_bounds__(512) __attribute__((amdgpu_waves_per_eu(4, 4)))
void critic_kernel(
    const float* __restrict__ obs, const float* __restrict__ ag,
    const float* __restrict__ g,   const float* __restrict__ anchor,
    const float* __restrict__ act,
    const float* __restrict__ b1,  const float* __restrict__ b2,
    const float* __restrict__ b3,  const float* __restrict__ b4,
    const float* __restrict__ b5,  const float* __restrict__ b7,
    const float* __restrict__ w6,  const float* __restrict__ b6,
    const float* __restrict__ w8,  const float* __restrict__ b8,
    const u16* __restrict__ wsz, float* __restrict__ out, int B) {

    __shared__ u16 pool[H_OFF + 96 * 256];   // 30720 u16 = 61440 B

    const int t    = threadIdx.x;
    const int lane = t & 63;
    const int wave = t >> 6;     // 0..7
    const int wr   = wave >> 2;  // 0,1 : batch-lane half / rho net
    const int wc   = wave & 3;   // 0..3: 4 column-tiles
    const int lr   = lane & 15;
    const int lg   = lane >> 4;
    const int wg   = blockIdx.x;
    const int swr  = (lr & 7) << 3;   // row-XOR swizzle (h/inp rows are ..*16+lr)

    // ---- Gather: build pair inputs (96 rows x 54, pad to 64), swizzled.
    // 2 threads/row: part 0 -> cols [0,32), part 1 -> cols [32,64).
    if (t < 192) {
        const int O1[3] = {0, 0, 1}, O2[3] = {1, 2, 2};
        const int JA[3] = {3, 4, 6}, KA[3] = {5, 7, 8};
        int rr = t >> 1, part = t & 1;
        int p = rr >> 5, bl = rr & 31;
        int b = wg * 32 + bl;
        int j = JA[p], k = KA[p];
        bool sel = (anchor[b * 9 + j] - anchor[b * 9 + k]) >= 0.0f;
        u16* row = &pool[rr * 64];
        const int sw = (rr & 7) << 3;
        const u16 ONE = 0x3F80;
        if (part == 0) {
            int bit2 = sel ? j : k;
            int oi = sel ? O1[p] : O2[p];
            row[0 ^ sw] = f2b(ag[b * 9 + p]);
            row[1 ^ sw] = f2b(ag[b * 9 + bit2]);
            row[2 ^ sw] = f2b(g[b * 9 + p]);
            row[3 ^ sw] = f2b(g[b * 9 + bit2]);
            for (int c = 0; c < 10; ++c) row[(4 + c) ^ sw] = f2b(obs[b * 55 + c]);
            row[14 ^ sw] = (oi == 0) ? ONE : 0;
            row[15 ^ sw] = (oi == 1) ? ONE : 0;
            row[16 ^ sw] = (oi == 2) ? ONE : 0;
            for (int c = 0; c < 15; ++c) row[(17 + c) ^ sw] = f2b(obs[b * 55 + 10 + 15 * oi + c]);
        } else {
            int oj = sel ? O2[p] : O1[p];
            row[32 ^ sw] = (oj == 0) ? ONE : 0;
            row[33 ^ sw] = (oj == 1) ? ONE : 0;
            row[34 ^ sw] = (oj == 2) ? ONE : 0;
            for (int c = 0; c < 15; ++c) row[(35 + c) ^ sw] = f2b(obs[b * 55 + 10 + 15 * oj + c]);
            for (int c = 0; c < 4; ++c)  row[(50 + c) ^ sw] = f2b(act[b * 4 + c]);
            for (int c = 54; c < 64; ++c) row[c ^ sw] = 0;
        }
    }
    __syncthreads();

    u32 s1w[4][2];    // net0 pair-sums, packed bf16 pairs (hidden-adjacent)
    u32 s2w[4][2];    // net1 pair-sums

    // ---- Phi networks (net 0: w1/w2, net 1: w3/w4) ----
    for (int net = 0; net < 2; ++net) {
        const u16* Wl1 = wsz + (net ? 16384 : 0);
        const u16* Wl2 = wsz + 32768 + (net ? 65536 : 0);
        const float* bl1 = net ? b3 : b1;
        const float* bl2 = net ? b4 : b2;

        // Layer 1: A=W1^T frags, B=inp rows rt=2p+wr. D=(batch=lr, hid=lg*4+reg)
        f4 acc[3][4];
        #pragma unroll
        for (int p = 0; p < 3; ++p)
            #pragma unroll
            for (int c = 0; c < 4; ++c) acc[p][c] = (f4){0.f, 0.f, 0.f, 0.f};
        __builtin_amdgcn_s_setprio(1);
        #pragma unroll 1
        for (int kt = 0; kt < 2; ++kt) {
            bf8 wfr[4];
            #pragma unroll
            for (int c = 0; c < 4; ++c)
                wfr[c] = *(const bf8*)(Wl1 + (size_t)(((kt * 16 + wc * 4 + c) * 64 + lane) * 8));
            #pragma unroll
            for (int p = 0; p < 3; ++p) {
                bf8 xfr = *(const bf8*)(&pool[((2 * p + wr) * 16 + lr) * 64 + ((kt * 32 + lg * 8) ^ swr)]);
                #pragma unroll
                for (int c = 0; c < 4; ++c)
                    acc[p][c] = __builtin_amdgcn_mfma_f32_16x16x32_bf16(wfr[c], xfr, acc[p][c], 0, 0, 0);
            }
        }
        __builtin_amdgcn_s_setprio(0);
        #pragma unroll
        for (int c = 0; c < 4; ++c) {
            float4 bv = *(const float4*)(bl1 + (wc * 4 + c) * 16 + lg * 4);
            #pragma unroll
            for (int p = 0; p < 3; ++p) {
                uint2 w;
                w.x = pk2(fmaxf(acc[p][c][0] + bv.x, 0.f), fmaxf(acc[p][c][1] + bv.y, 0.f));
                w.y = pk2(fmaxf(acc[p][c][2] + bv.z, 0.f), fmaxf(acc[p][c][3] + bv.w, 0.f));
                *(uint2*)&pool[H_OFF + ((2 * p + wr) * 16 + lr) * 256 + ((((wc * 4 + c) * 16) + lg * 4) ^ swr)] = w;
            }
        }
        __syncthreads();

        // Layer 2: A=W2^T frags, B=h rows rt=2p+wr. Relu + in-register pair-sum.
        // unroll 2: caps in-flight W-frag loads at 8 (32 VGPRs) -> no spill.
        f4 acc2[3][4];
        #pragma unroll
        for (int p = 0; p < 3; ++p)
            #pragma unroll
            for (int c = 0; c < 4; ++c) acc2[p][c] = (f4){0.f, 0.f, 0.f, 0.f};
        __builtin_amdgcn_s_setprio(1);
        #pragma unroll 2
        for (int ks = 0; ks < 8; ++ks) {
            bf8 wfr[4];
            #pragma unroll
            for (int c = 0; c < 4; ++c)
                wfr[c] = *(const bf8*)(Wl2 + (size_t)(((ks * 16 + wc * 4 + c) * 64 + lane) * 8));
            #pragma unroll
            for (int p = 0; p < 3; ++p) {
                bf8 hfr = *(const bf8*)(&pool[H_OFF + ((2 * p + wr) * 16 + lr) * 256 + ((ks * 32 + lg * 8) ^ swr)]);
                #pragma unroll
                for (int c = 0; c < 4; ++c)
                    acc2[p][c] = __builtin_amdgcn_mfma_f32_16x16x32_bf16(wfr[c], hfr, acc2[p][c], 0, 0, 0);
            }
        }
        __builtin_amdgcn_s_setprio(0);
        #pragma unroll
        for (int c = 0; c < 4; ++c) {
            float4 bv = *(const float4*)(bl2 + (wc * 4 + c) * 16 + lg * 4);
            f4 sv = (f4){0.f, 0.f, 0.f, 0.f};
            #pragma unroll
            for (int p = 0; p < 3; ++p) {
                sv[0] += fmaxf(acc2[p][c][0] + bv.x, 0.f);
                sv[1] += fmaxf(acc2[p][c][1] + bv.y, 0.f);
                sv[2] += fmaxf(acc2[p][c][2] + bv.z, 0.f);
                sv[3] += fmaxf(acc2[p][c][3] + bv.w, 0.f);
            }
            if (net == 0) {
                s1w[c][0] = pk2(sv[0], sv[1]);
                s1w[c][1] = pk2(sv[2], sv[3]);
            } else {
                s2w[c][0] = pk2(sv[0], sv[1]);
                s2w[c][1] = pk2(sv[2], sv[3]);
            }
        }
        __syncthreads();  // h reads done before next net overwrites h
    }

    // ---- Write S1 (rows 0..31), S2 (rows 32..63): one b64 each ----
    #pragma unroll
    for (int c = 0; c < 4; ++c) {
        int base = H_OFF + (wr * 16 + lr) * 256 + ((((wc * 4 + c) * 16) + lg * 4) ^ swr);
        *(uint2*)&pool[base]       = *(uint2*)&s1w[c][0];
        *(uint2*)&pool[base + S2O] = *(uint2*)&s2w[c][0];
    }
    __syncthreads();

    // ---- Rho hidden layer: wr picks the net (wr=0: S1/W5, wr=1: S2/W7) ----
    {
        const u16* Wr   = wsz + (wr ? 229376 : 163840);
        const int soff  = wr ? S2O : 0;
        const float* br = wr ? b7 : b5;
        f4 racc[2][4];
        #pragma unroll
        for (int rt = 0; rt < 2; ++rt)
            #pragma unroll
            for (int c = 0; c < 4; ++c) racc[rt][c] = (f4){0.f, 0.f, 0.f, 0.f};
        __builtin_amdgcn_s_setprio(1);
        #pragma unroll 2
        for (int ks = 0; ks < 8; ++ks) {
            bf8 wf[4];
            #pragma unroll
            for (int c = 0; c < 4; ++c)
                wf[c] = *(const bf8*)(Wr + (size_t)(((ks * 16 + wc * 4 + c) * 64 + lane) * 8));
            #pragma unroll
            for (int rt = 0; rt < 2; ++rt) {
                bf8 sf = *(const bf8*)(&pool[H_OFF + soff + (rt * 16 + lr) * 256 + ((ks * 32 + lg * 8) ^ swr)]);
                #pragma unroll
                for (int c = 0; c < 4; ++c)
                    racc[rt][c] = __builtin_amdgcn_mfma_f32_16x16x32_bf16(wf[c], sf, racc[rt][c], 0, 0, 0);
            }
        }
        __builtin_amdgcn_s_setprio(0);
        // Pack bias+relu+bf16 BEFORE the barrier: 32 f32 -> 16 u32 live regs.
        uint2 rw[2][4];
        #pragma unroll
        for (int c = 0; c < 4; ++c) {
            float4 bv = *(const float4*)(br + (wc * 4 + c) * 16 + lg * 4);
            #pragma unroll
            for (int rt = 0; rt < 2; ++rt) {
                rw[rt][c].x = pk2(fmaxf(racc[rt][c][0] + bv.x, 0.f), fmaxf(racc[rt][c][1] + bv.y, 0.f));
                rw[rt][c].y = pk2(fmaxf(racc[rt][c][2] + bv.z, 0.f), fmaxf(racc[rt][c][3] + bv.w, 0.f));
            }
        }
        // net0 (wr=0) -> RH0 (rows 64..95; disjoint from S reads -> no barrier)
        if (wr == 0) {
            #pragma unroll
            for (int c = 0; c < 4; ++c)
                #pragma unroll
                for (int rt = 0; rt < 2; ++rt)
                    *(uint2*)&pool[H_OFF + RH0O + (rt * 16 + lr) * 256 + ((((wc * 4 + c) * 16) + lg * 4) ^ swr)] = rw[rt][c];
        }
        __syncthreads();   // all S1 reads done before net1 overwrites it
        // net1 (wr=1) -> RH1 (over consumed S1, rows 0..31)
        if (wr == 1) {
            #pragma unroll
            for (int c = 0; c < 4; ++c)
                #pragma unroll
                for (int rt = 0; rt < 2; ++rt)
                    *(uint2*)&pool[H_OFF + (rt * 16 + lr) * 256 + ((((wc * 4 + c) * 16) + lg * 4) ^ swr)] = rw[rt][c];
        }
        __syncthreads();
    }

    // ---- Final dots, split-K over 8 waves: q = rhoH @ w6 + b6. FP32 OUT ----
    {
        int net = lane >> 5, r = lane & 31;
        int hoff = net ? H_OFF : H_OFF + RH0O;
        const float* wv = net ? w8 : w6;
        const int swq = (r & 7) << 3;
        float s = 0.f;
        #pragma unroll
        for (int it = 0; it < 8; ++it) {
            uint2 two = *(const uint2*)&pool[hoff + r * 256 + ((wave * 32 + it * 4) ^ swq)];
            float4 wq = *(const float4*)(wv + wave * 32 + it * 4);
            s += __uint_as_float(two.x << 16)          * wq.x;
            s += __uint_as_float(two.x & 0xffff0000u)  * wq.y;
            s += __uint_as_float(two.y << 16)          * wq.z;
            s += __uint_as_float(two.y & 0xffff0000u)  * wq.w;
        }
        ((u32*)pool)[t] = __float_as_uint(s);   // partials in dead inp region
    }
    __syncthreads();
    if (t < 64) {
        int net = t >> 5, r = t & 31;
        float qv = net ? b8[0] : b6[0];
        #pragma unroll
        for (int p = 0; p < 8; ++p)
            qv += __uint_as_float(((u32*)pool)[p * 64 + t]);
        out[net * B + wg * 32 + r] = qv;
    }
}

extern "C" void kernel_launch(void* const* d_in, const int* in_sizes, int n_in,
                              void* d_out, int out_size, void* d_ws, size_t ws_size,
                              hipStream_t stream) {
    const float* obs = (const float*)d_in[0];
    const float* ag  = (const float*)d_in[1];
    const float* g   = (const float*)d_in[2];
    const float* anc = (const float*)d_in[3];
    const float* act = (const float*)d_in[4];
    const float* w1  = (const float*)d_in[5];
    const float* b1  = (const float*)d_in[6];
    const float* w2  = (const float*)d_in[7];
    const float* b2  = (const float*)d_in[8];
    const float* w3  = (const float*)d_in[9];
    const float* b3  = (const float*)d_in[10];
    const float* w4  = (const float*)d_in[11];
    const float* b4  = (const float*)d_in[12];
    const float* w5  = (const float*)d_in[13];
    const float* b5  = (const float*)d_in[14];
    const float* w6  = (const float*)d_in[15];
    const float* b6  = (const float*)d_in[16];
    const float* w7  = (const float*)d_in[17];
    const float* b7  = (const float*)d_in[18];
    const float* w8  = (const float*)d_in[19];
    const float* b8  = (const float*)d_in[20];
    u16* ws    = (u16*)d_ws;
    float* out = (float*)d_out;
    int B = in_sizes[0] / 55;

    swz_all<<<36, 256, 0, stream>>>(w1, w3, w2, w4, w5, w7, ws);
    critic_kernel<<<(B + 31) / 32, 512, 0, stream>>>(obs, ag, g, anc, act,
                                                     b1, b2, b3, b4, b5, b7,
                                                     w6, b6, w8, b8, ws, out, B);
}

// Round 11
// 201.838 us; speedup vs baseline: 1.8685x; 1.0512x over previous
//
#include <hip/hip_runtime.h>
#include <hip/hip_bf16.h>

typedef unsigned short u16;
typedef unsigned int   u32;

using bf8 = __attribute__((ext_vector_type(8))) __bf16;
using f4  = __attribute__((ext_vector_type(4))) float;

__device__ __forceinline__ float b2f(u16 u) {
    union { u32 i; float f; } v; v.i = ((u32)u) << 16; return v.f;
}
__device__ __forceinline__ u16 f2b(float f) {
    union { float f; u32 i; } v; v.f = f;
    u32 x = v.i;
    x += 0x7fffu + ((x >> 16) & 1u);   // RNE
    return (u16)(x >> 16);
}
// Packed fp32x2 -> bf16x2 (low = first arg).
__device__ __forceinline__ u32 pk2(float lo, float hi) {
    union { __hip_bfloat162 h; u32 u; } v;
    v.h = __float22bfloat162_rn(make_float2(lo, hi));
    return v.u;
}

// ---------------------------------------------------------------------------
// Weight swizzle (verified layout — unchanged; frags used as A-operands):
// dst[((kt*16+ct)*64+lane)*8+j] = bf16(W[kt*32+(lane>>4)*8+j][ct*16+(lane&15)])
// ---------------------------------------------------------------------------
__global__ void swz_all(const float* __restrict__ w1, const float* __restrict__ w3,
                        const float* __restrict__ w2, const float* __restrict__ w4,
                        const float* __restrict__ w5, const float* __restrict__ w7,
                        u16* __restrict__ ws) {
    __shared__ u16 slab[32 * 270];
    int b = blockIdx.x, t = threadIdx.x;
    const float* src; u16* dst; int kmax, kt;
    if      (b <  2) { src = w1; dst = ws;          kmax = 54;  kt = b;      }
    else if (b <  4) { src = w3; dst = ws + 16384;  kmax = 54;  kt = b - 2;  }
    else if (b < 12) { src = w2; dst = ws + 32768;  kmax = 256; kt = b - 4;  }
    else if (b < 20) { src = w4; dst = ws + 98304;  kmax = 256; kt = b - 12; }
    else if (b < 28) { src = w5; dst = ws + 163840; kmax = 256; kt = b - 20; }
    else             { src = w7; dst = ws + 229376; kmax = 256; kt = b - 28; }

    #pragma unroll
    for (int it = 0; it < 8; ++it) {
        int flat = it * 1024 + t * 4;
        int row = flat >> 8, col = flat & 255;
        int k = kt * 32 + row;
        float4 v = make_float4(0.f, 0.f, 0.f, 0.f);
        if (k < kmax) v = *(const float4*)(src + k * 256 + col);
        u32* sp = (u32*)&slab[row * 270 + col];
        sp[0] = pk2(v.x, v.y);
        sp[1] = pk2(v.z, v.w);
    }
    __syncthreads();

    int lane = t & 63, wave = t >> 6, lr = lane & 15, kg = lane >> 4;
    #pragma unroll
    for (int i = 0; i < 4; ++i) {
        int ct = wave * 4 + i;
        u16 v[8];
        #pragma unroll
        for (int j = 0; j < 8; ++j)
            v[j] = slab[(kg * 8 + j) * 270 + ct * 16 + lr];
        uint4 o;
        o.x = (u32)v[0] | ((u32)v[1] << 16);
        o.y = (u32)v[2] | ((u32)v[3] << 16);
        o.z = (u32)v[4] | ((u32)v[5] << 16);
        o.w = (u32)v[6] | ((u32)v[7] << 16);
        *(uint4*)(dst + (size_t)(((kt * 16 + ct) * 64 + lane) * 8)) = o;
    }
}

// ---------------------------------------------------------------------------
// Fused critic, operand-swapped MFMA. 512 thr / 8 waves, 2-D wave split:
//   wr = wave>>2 : batch-lane half (rt = 2p+wr -> batch lanes wr*16+lr)
//   wc = wave&3  : 4 hidden column-tiles (ct = wc*4+c)
// Each LDS B-fragment read feeds 4 MFMAs -> b128 traffic 1120 -> 608 per WG.
//
// REGALLOC history: full unroll on ks loops -> compiler hoists ALL wfr[4]
// loads (128 VGPRs in flight) -> 300 MB spill (R4/R8). unroll 2 -> 78 MB
// spill, 123 us (R9): pipelining still holds 2-3 load batches + 48-reg acc
// > 128 budget. THIS round: unroll 1 -> <=2 batches x 16 VGPRs in flight,
// peak ~105 < 128 -> no spill. 12-16 MFMAs per iteration dwarf the loop
// overhead; weights are L2-resident.
//
// LDS layout (u16), activation rows XOR-swizzled:
//   physical = row*stride + (logical_col ^ ((row&7)<<3))
//   inp: rows 0..95, stride 64  ([0, 6144))
//   h  : rows 0..95, stride 256 ([6144, +24576))
//        S1 rows 0..31, S2 rows 32..63, RH0 rows 64..95, RH1 over S1.
// Total 61440 B -> 2 blocks/CU, 4 waves/SIMD.
// ---------------------------------------------------------------------------
#define H_OFF 6144
#define S2O   (32 * 256)
#define RH0O  (64 * 256)

__global__ __launch_bounds__(512) __attribute__((amdgpu_waves_per_eu(4, 4)))
void critic_kernel(
    const float* __restrict__ obs, const float* __restrict__ ag,
    const float* __restrict__ g,   const float* __restrict__ anchor,
    const float* __restrict__ act,
    const float* __restrict__ b1,  const float* __restrict__ b2,
    const float* __restrict__ b3,  const float* __restrict__ b4,
    const float* __restrict__ b5,  const float* __restrict__ b7,
    const float* __restrict__ w6,  const float* __restrict__ b6,
    const float* __restrict__ w8,  const float* __restrict__ b8,
    const u16* __restrict__ wsz, float* __restrict__ out, int B) {

    __shared__ u16 pool[H_OFF + 96 * 256];   // 30720 u16 = 61440 B

    const int t    = threadIdx.x;
    const int lane = t & 63;
    const int wave = t >> 6;     // 0..7
    const int wr   = wave >> 2;  // 0,1 : batch-lane half / rho net
    const int wc   = wave & 3;   // 0..3: 4 column-tiles
    const int lr   = lane & 15;
    const int lg   = lane >> 4;
    const int wg   = blockIdx.x;
    const int swr  = (lr & 7) << 3;   // row-XOR swizzle (h/inp rows are ..*16+lr)

    // ---- Gather: build pair inputs (96 rows x 54, pad to 64), swizzled.
    // 2 threads/row: part 0 -> cols [0,32), part 1 -> cols [32,64).
    if (t < 192) {
        const int O1[3] = {0, 0, 1}, O2[3] = {1, 2, 2};
        const int JA[3] = {3, 4, 6}, KA[3] = {5, 7, 8};
        int rr = t >> 1, part = t & 1;
        int p = rr >> 5, bl = rr & 31;
        int b = wg * 32 + bl;
        int j = JA[p], k = KA[p];
        bool sel = (anchor[b * 9 + j] - anchor[b * 9 + k]) >= 0.0f;
        u16* row = &pool[rr * 64];
        const int sw = (rr & 7) << 3;
        const u16 ONE = 0x3F80;
        if (part == 0) {
            int bit2 = sel ? j : k;
            int oi = sel ? O1[p] : O2[p];
            row[0 ^ sw] = f2b(ag[b * 9 + p]);
            row[1 ^ sw] = f2b(ag[b * 9 + bit2]);
            row[2 ^ sw] = f2b(g[b * 9 + p]);
            row[3 ^ sw] = f2b(g[b * 9 + bit2]);
            for (int c = 0; c < 10; ++c) row[(4 + c) ^ sw] = f2b(obs[b * 55 + c]);
            row[14 ^ sw] = (oi == 0) ? ONE : 0;
            row[15 ^ sw] = (oi == 1) ? ONE : 0;
            row[16 ^ sw] = (oi == 2) ? ONE : 0;
            for (int c = 0; c < 15; ++c) row[(17 + c) ^ sw] = f2b(obs[b * 55 + 10 + 15 * oi + c]);
        } else {
            int oj = sel ? O2[p] : O1[p];
            row[32 ^ sw] = (oj == 0) ? ONE : 0;
            row[33 ^ sw] = (oj == 1) ? ONE : 0;
            row[34 ^ sw] = (oj == 2) ? ONE : 0;
            for (int c = 0; c < 15; ++c) row[(35 + c) ^ sw] = f2b(obs[b * 55 + 10 + 15 * oj + c]);
            for (int c = 0; c < 4; ++c)  row[(50 + c) ^ sw] = f2b(act[b * 4 + c]);
            for (int c = 54; c < 64; ++c) row[c ^ sw] = 0;
        }
    }
    __syncthreads();

    u32 s1w[4][2];    // net0 pair-sums, packed bf16 pairs (hidden-adjacent)
    u32 s2w[4][2];    // net1 pair-sums

    // ---- Phi networks (net 0: w1/w2, net 1: w3/w4) ----
    for (int net = 0; net < 2; ++net) {
        const u16* Wl1 = wsz + (net ? 16384 : 0);
        const u16* Wl2 = wsz + 32768 + (net ? 65536 : 0);
        const float* bl1 = net ? b3 : b1;
        const float* bl2 = net ? b4 : b2;

        // Layer 1: A=W1^T frags, B=inp rows rt=2p+wr. D=(batch=lr, hid=lg*4+reg)
        f4 acc[3][4];
        #pragma unroll
        for (int p = 0; p < 3; ++p)
            #pragma unroll
            for (int c = 0; c < 4; ++c) acc[p][c] = (f4){0.f, 0.f, 0.f, 0.f};
        __builtin_amdgcn_s_setprio(1);
        #pragma unroll 1
        for (int kt = 0; kt < 2; ++kt) {
            bf8 wfr[4];
            #pragma unroll
            for (int c = 0; c < 4; ++c)
                wfr[c] = *(const bf8*)(Wl1 + (size_t)(((kt * 16 + wc * 4 + c) * 64 + lane) * 8));
            #pragma unroll
            for (int p = 0; p < 3; ++p) {
                bf8 xfr = *(const bf8*)(&pool[((2 * p + wr) * 16 + lr) * 64 + ((kt * 32 + lg * 8) ^ swr)]);
                #pragma unroll
                for (int c = 0; c < 4; ++c)
                    acc[p][c] = __builtin_amdgcn_mfma_f32_16x16x32_bf16(wfr[c], xfr, acc[p][c], 0, 0, 0);
            }
        }
        __builtin_amdgcn_s_setprio(0);
        #pragma unroll
        for (int c = 0; c < 4; ++c) {
            float4 bv = *(const float4*)(bl1 + (wc * 4 + c) * 16 + lg * 4);
            #pragma unroll
            for (int p = 0; p < 3; ++p) {
                uint2 w;
                w.x = pk2(fmaxf(acc[p][c][0] + bv.x, 0.f), fmaxf(acc[p][c][1] + bv.y, 0.f));
                w.y = pk2(fmaxf(acc[p][c][2] + bv.z, 0.f), fmaxf(acc[p][c][3] + bv.w, 0.f));
                *(uint2*)&pool[H_OFF + ((2 * p + wr) * 16 + lr) * 256 + ((((wc * 4 + c) * 16) + lg * 4) ^ swr)] = w;
            }
        }
        __syncthreads();

        // Layer 2: A=W2^T frags, B=h rows rt=2p+wr. Relu + in-register pair-sum.
        // unroll 1: <=2 pipelined load batches (32 VGPRs) in flight -> no spill.
        f4 acc2[3][4];
        #pragma unroll
        for (int p = 0; p < 3; ++p)
            #pragma unroll
            for (int c = 0; c < 4; ++c) acc2[p][c] = (f4){0.f, 0.f, 0.f, 0.f};
        __builtin_amdgcn_s_setprio(1);
        #pragma unroll 1
        for (int ks = 0; ks < 8; ++ks) {
            bf8 wfr[4];
            #pragma unroll
            for (int c = 0; c < 4; ++c)
                wfr[c] = *(const bf8*)(Wl2 + (size_t)(((ks * 16 + wc * 4 + c) * 64 + lane) * 8));
            #pragma unroll
            for (int p = 0; p < 3; ++p) {
                bf8 hfr = *(const bf8*)(&pool[H_OFF + ((2 * p + wr) * 16 + lr) * 256 + ((ks * 32 + lg * 8) ^ swr)]);
                #pragma unroll
                for (int c = 0; c < 4; ++c)
                    acc2[p][c] = __builtin_amdgcn_mfma_f32_16x16x32_bf16(wfr[c], hfr, acc2[p][c], 0, 0, 0);
            }
        }
        __builtin_amdgcn_s_setprio(0);
        #pragma unroll
        for (int c = 0; c < 4; ++c) {
            float4 bv = *(const float4*)(bl2 + (wc * 4 + c) * 16 + lg * 4);
            f4 sv = (f4){0.f, 0.f, 0.f, 0.f};
            #pragma unroll
            for (int p = 0; p < 3; ++p) {
                sv[0] += fmaxf(acc2[p][c][0] + bv.x, 0.f);
                sv[1] += fmaxf(acc2[p][c][1] + bv.y, 0.f);
                sv[2] += fmaxf(acc2[p][c][2] + bv.z, 0.f);
                sv[3] += fmaxf(acc2[p][c][3] + bv.w, 0.f);
            }
            if (net == 0) {
                s1w[c][0] = pk2(sv[0], sv[1]);
                s1w[c][1] = pk2(sv[2], sv[3]);
            } else {
                s2w[c][0] = pk2(sv[0], sv[1]);
                s2w[c][1] = pk2(sv[2], sv[3]);
            }
        }
        __syncthreads();  // h reads done before next net overwrites h
    }

    // ---- Write S1 (rows 0..31), S2 (rows 32..63): one b64 each ----
    #pragma unroll
    for (int c = 0; c < 4; ++c) {
        int base = H_OFF + (wr * 16 + lr) * 256 + ((((wc * 4 + c) * 16) + lg * 4) ^ swr);
        *(uint2*)&pool[base]       = *(uint2*)&s1w[c][0];
        *(uint2*)&pool[base + S2O] = *(uint2*)&s2w[c][0];
    }
    __syncthreads();

    // ---- Rho hidden layer: wr picks the net (wr=0: S1/W5, wr=1: S2/W7) ----
    {
        const u16* Wr   = wsz + (wr ? 229376 : 163840);
        const int soff  = wr ? S2O : 0;
        const float* br = wr ? b7 : b5;
        f4 racc[2][4];
        #pragma unroll
        for (int rt = 0; rt < 2; ++rt)
            #pragma unroll
            for (int c = 0; c < 4; ++c) racc[rt][c] = (f4){0.f, 0.f, 0.f, 0.f};
        __builtin_amdgcn_s_setprio(1);
        #pragma unroll 1
        for (int ks = 0; ks < 8; ++ks) {
            bf8 wf[4];
            #pragma unroll
            for (int c = 0; c < 4; ++c)
                wf[c] = *(const bf8*)(Wr + (size_t)(((ks * 16 + wc * 4 + c) * 64 + lane) * 8));
            #pragma unroll
            for (int rt = 0; rt < 2; ++rt) {
                bf8 sf = *(const bf8*)(&pool[H_OFF + soff + (rt * 16 + lr) * 256 + ((ks * 32 + lg * 8) ^ swr)]);
                #pragma unroll
                for (int c = 0; c < 4; ++c)
                    racc[rt][c] = __builtin_amdgcn_mfma_f32_16x16x32_bf16(wf[c], sf, racc[rt][c], 0, 0, 0);
            }
        }
        __builtin_amdgcn_s_setprio(0);
        // Pack bias+relu+bf16 BEFORE the barrier: 32 f32 -> 16 u32 live regs.
        uint2 rw[2][4];
        #pragma unroll
        for (int c = 0; c < 4; ++c) {
            float4 bv = *(const float4*)(br + (wc * 4 + c) * 16 + lg * 4);
            #pragma unroll
            for (int rt = 0; rt < 2; ++rt) {
                rw[rt][c].x = pk2(fmaxf(racc[rt][c][0] + bv.x, 0.f), fmaxf(racc[rt][c][1] + bv.y, 0.f));
                rw[rt][c].y = pk2(fmaxf(racc[rt][c][2] + bv.z, 0.f), fmaxf(racc[rt][c][3] + bv.w, 0.f));
            }
        }
        // net0 (wr=0) -> RH0 (rows 64..95; disjoint from S reads -> no barrier)
        if (wr == 0) {
            #pragma unroll
            for (int c = 0; c < 4; ++c)
                #pragma unroll
                for (int rt = 0; rt < 2; ++rt)
                    *(uint2*)&pool[H_OFF + RH0O + (rt * 16 + lr) * 256 + ((((wc * 4 + c) * 16) + lg * 4) ^ swr)] = rw[rt][c];
        }
        __syncthreads();   // all S1 reads done before net1 overwrites it
        // net1 (wr=1) -> RH1 (over consumed S1, rows 0..31)
        if (wr == 1) {
            #pragma unroll
            for (int c = 0; c < 4; ++c)
                #pragma unroll
                for (int rt = 0; rt < 2; ++rt)
                    *(uint2*)&pool[H_OFF + (rt * 16 + lr) * 256 + ((((wc * 4 + c) * 16) + lg * 4) ^ swr)] = rw[rt][c];
        }
        __syncthreads();
    }

    // ---- Final dots, split-K over 8 waves: q = rhoH @ w6 + b6. FP32 OUT ----
    {
        int net = lane >> 5, r = lane & 31;
        int hoff = net ? H_OFF : H_OFF + RH0O;
        const float* wv = net ? w8 : w6;
        const int swq = (r & 7) << 3;
        float s = 0.f;
        #pragma unroll
        for (int it = 0; it < 8; ++it) {
            uint2 two = *(const uint2*)&pool[hoff + r * 256 + ((wave * 32 + it * 4) ^ swq)];
            float4 wq = *(const float4*)(wv + wave * 32 + it * 4);
            s += __uint_as_float(two.x << 16)          * wq.x;
            s += __uint_as_float(two.x & 0xffff0000u)  * wq.y;
            s += __uint_as_float(two.y << 16)          * wq.z;
            s += __uint_as_float(two.y & 0xffff0000u)  * wq.w;
        }
        ((u32*)pool)[t] = __float_as_uint(s);   // partials in dead inp region
    }
    __syncthreads();
    if (t < 64) {
        int net = t >> 5, r = t & 31;
        float qv = net ? b8[0] : b6[0];
        #pragma unroll
        for (int p = 0; p < 8; ++p)
            qv += __uint_as_float(((u32*)pool)[p * 64 + t]);
        out[net * B + wg * 32 + r] = qv;
    }
}

extern "C" void kernel_launch(void* const* d_in, const int* in_sizes, int n_in,
                              void* d_out, int out_size, void* d_ws, size_t ws_size,
                              hipStream_t stream) {
    const float* obs = (const float*)d_in[0];
    const float* ag  = (const float*)d_in[1];
    const float* g   = (const float*)d_in[2];
    const float* anc = (const float*)d_in[3];
    const float* act = (const float*)d_in[4];
    const float* w1  = (const float*)d_in[5];
    const float* b1  = (const float*)d_in[6];
    const float* w2  = (const float*)d_in[7];
    const float* b2  = (const float*)d_in[8];
    const float* w3  = (const float*)d_in[9];
    const float* b3  = (const float*)d_in[10];
    const float* w4  = (const float*)d_in[11];
    const float* b4  = (const float*)d_in[12];
    const float* w5  = (const float*)d_in[13];
    const float* b5  = (const float*)d_in[14];
    const float* w6  = (const float*)d_in[15];
    const float* b6  = (const float*)d_in[16];
    const float* w7  = (const float*)d_in[17];
    const float* b7  = (const float*)d_in[18];
    const float* w8  = (const float*)d_in[19];
    const float* b8  = (const float*)d_in[20];
    u16* ws    = (u16*)d_ws;
    float* out = (float*)d_out;
    int B = in_sizes[0] / 55;

    swz_all<<<36, 256, 0, stream>>>(w1, w3, w2, w4, w5, w7, ws);
    critic_kernel<<<(B + 31) / 32, 512, 0, stream>>>(obs, ag, g, anc, act,
                                                     b1, b2, b3, b4, b5, b7,
                                                     w6, b6, w8, b8, ws, out, B);
}

// Round 13
// 198.658 us; speedup vs baseline: 1.8984x; 1.0160x over previous
//
#include <hip/hip_runtime.h>
#include <hip/hip_bf16.h>

typedef unsigned short u16;
typedef unsigned int   u32;

using bf8 = __attribute__((ext_vector_type(8))) __bf16;
using f4  = __attribute__((ext_vector_type(4))) float;

__device__ __forceinline__ float b2f(u16 u) {
    union { u32 i; float f; } v; v.i = ((u32)u) << 16; return v.f;
}
__device__ __forceinline__ u16 f2b(float f) {
    union { float f; u32 i; } v; v.f = f;
    u32 x = v.i;
    x += 0x7fffu + ((x >> 16) & 1u);   // RNE
    return (u16)(x >> 16);
}
// Packed fp32x2 -> bf16x2 (low = first arg).
__device__ __forceinline__ u32 pk2(float lo, float hi) {
    union { __hip_bfloat162 h; u32 u; } v;
    v.h = __float22bfloat162_rn(make_float2(lo, hi));
    return v.u;
}

// ---------------------------------------------------------------------------
// Weight swizzle (verified layout — unchanged; frags used as A-operands):
// dst[((kt*16+ct)*64+lane)*8+j] = bf16(W[kt*32+(lane>>4)*8+j][ct*16+(lane&15)])
// ---------------------------------------------------------------------------
__global__ void swz_all(const float* __restrict__ w1, const float* __restrict__ w3,
                        const float* __restrict__ w2, const float* __restrict__ w4,
                        const float* __restrict__ w5, const float* __restrict__ w7,
                        u16* __restrict__ ws) {
    __shared__ u16 slab[32 * 270];
    int b = blockIdx.x, t = threadIdx.x;
    const float* src; u16* dst; int kmax, kt;
    if      (b <  2) { src = w1; dst = ws;          kmax = 54;  kt = b;      }
    else if (b <  4) { src = w3; dst = ws + 16384;  kmax = 54;  kt = b - 2;  }
    else if (b < 12) { src = w2; dst = ws + 32768;  kmax = 256; kt = b - 4;  }
    else if (b < 20) { src = w4; dst = ws + 98304;  kmax = 256; kt = b - 12; }
    else if (b < 28) { src = w5; dst = ws + 163840; kmax = 256; kt = b - 20; }
    else             { src = w7; dst = ws + 229376; kmax = 256; kt = b - 28; }

    #pragma unroll
    for (int it = 0; it < 8; ++it) {
        int flat = it * 1024 + t * 4;
        int row = flat >> 8, col = flat & 255;
        int k = kt * 32 + row;
        float4 v = make_float4(0.f, 0.f, 0.f, 0.f);
        if (k < kmax) v = *(const float4*)(src + k * 256 + col);
        u32* sp = (u32*)&slab[row * 270 + col];
        sp[0] = pk2(v.x, v.y);
        sp[1] = pk2(v.z, v.w);
    }
    __syncthreads();

    int lane = t & 63, wave = t >> 6, lr = lane & 15, kg = lane >> 4;
    #pragma unroll
    for (int i = 0; i < 4; ++i) {
        int ct = wave * 4 + i;
        u16 v[8];
        #pragma unroll
        for (int j = 0; j < 8; ++j)
            v[j] = slab[(kg * 8 + j) * 270 + ct * 16 + lr];
        uint4 o;
        o.x = (u32)v[0] | ((u32)v[1] << 16);
        o.y = (u32)v[2] | ((u32)v[3] << 16);
        o.z = (u32)v[4] | ((u32)v[5] << 16);
        o.w = (u32)v[6] | ((u32)v[7] << 16);
        *(uint4*)(dst + (size_t)(((kt * 16 + ct) * 64 + lane) * 8)) = o;
    }
}

// ---------------------------------------------------------------------------
// Fused critic, operand-swapped MFMA. 512 thr / 8 waves, 2-D wave split:
//   wr = wave>>2 : batch-lane half (rt = 2p+wr -> batch lanes wr*16+lr)
//   wc = wave&3  : 4 hidden column-tiles (ct = wc*4+c)
//
// REGALLOC (R11 post-mortem): peak live ~142 > 128 budget -> 59 MB residual
// spill. The long-lived item is s1w (net0 pair-sums held across ALL of
// net1). FIX: use the spare 16 KB of LDS (160KB/CU - 2x61440B = 37KB free)
// as a dedicated S1 region (SB): net0's pair-sums are written to LDS
// immediately, s1w registers die at once -> peak ~124 < 128, no spill.
// LDS/block 77824 B; 2 blocks/CU still fit (155648 <= 163840).
// Bonus: RH1 now overwrites dead h rows (S1 lives in SB), so the rho
// phase needs only ONE barrier.
//
// LDS layout (u16), activation rows XOR-swizzled:
//   physical = row*stride + (logical_col ^ ((row&7)<<3))
//   inp: rows 0..95, stride 64  ([0, 6144))
//   h  : rows 0..95, stride 256 ([6144, 6144+24576))
//        S2 rows 32..63, RH0 rows 64..95, RH1 rows 0..31 (dead h)
//   SB : rows 0..31, stride 256 ([30720, 38912))  <- S1 early-evict region
// ---------------------------------------------------------------------------
#define H_OFF 6144
#define S2O   (32 * 256)
#define RH0O  (64 * 256)
#define SBO   (H_OFF + 96 * 256)

__global__ __launch_bounds__(512) __attribute__((amdgpu_waves_per_eu(4, 4)))
void critic_kernel(
    const float* __restrict__ obs, const float* __restrict__ ag,
    const float* __restrict__ g,   const float* __restrict__ anchor,
    const float* __restrict__ act,
    const float* __restrict__ b1,  const float* __restrict__ b2,
    const float* __restrict__ b3,  const float* __restrict__ b4,
    const float* __restrict__ b5,  const float* __restrict__ b7,
    const float* __restrict__ w6,  const float* __restrict__ b6,
    const float* __restrict__ w8,  const float* __restrict__ b8,
    const u16* __restrict__ wsz, float* __restrict__ out, int B) {

    __shared__ u16 pool[SBO + 32 * 256];   // 38912 u16 = 77824 B

    const int t    = threadIdx.x;
    const int lane = t & 63;
    const int wave = t >> 6;     // 0..7
    const int wr   = wave >> 2;  // 0,1 : batch-lane half / rho net
    const int wc   = wave & 3;   // 0..3: 4 column-tiles
    const int lr   = lane & 15;
    const int lg   = lane >> 4;
    const int wg   = blockIdx.x;
    const int swr  = (lr & 7) << 3;   // row-XOR swizzle (h/inp rows are ..*16+lr)

    // ---- Gather: build pair inputs (96 rows x 54, pad to 64), swizzled.
    // 2 threads/row: part 0 -> cols [0,32), part 1 -> cols [32,64).
    if (t < 192) {
        const int O1[3] = {0, 0, 1}, O2[3] = {1, 2, 2};
        const int JA[3] = {3, 4, 6}, KA[3] = {5, 7, 8};
        int rr = t >> 1, part = t & 1;
        int p = rr >> 5, bl = rr & 31;
        int b = wg * 32 + bl;
        int j = JA[p], k = KA[p];
        bool sel = (anchor[b * 9 + j] - anchor[b * 9 + k]) >= 0.0f;
        u16* row = &pool[rr * 64];
        const int sw = (rr & 7) << 3;
        const u16 ONE = 0x3F80;
        if (part == 0) {
            int bit2 = sel ? j : k;
            int oi = sel ? O1[p] : O2[p];
            row[0 ^ sw] = f2b(ag[b * 9 + p]);
            row[1 ^ sw] = f2b(ag[b * 9 + bit2]);
            row[2 ^ sw] = f2b(g[b * 9 + p]);
            row[3 ^ sw] = f2b(g[b * 9 + bit2]);
            for (int c = 0; c < 10; ++c) row[(4 + c) ^ sw] = f2b(obs[b * 55 + c]);
            row[14 ^ sw] = (oi == 0) ? ONE : 0;
            row[15 ^ sw] = (oi == 1) ? ONE : 0;
            row[16 ^ sw] = (oi == 2) ? ONE : 0;
            for (int c = 0; c < 15; ++c) row[(17 + c) ^ sw] = f2b(obs[b * 55 + 10 + 15 * oi + c]);
        } else {
            int oj = sel ? O2[p] : O1[p];
            row[32 ^ sw] = (oj == 0) ? ONE : 0;
            row[33 ^ sw] = (oj == 1) ? ONE : 0;
            row[34 ^ sw] = (oj == 2) ? ONE : 0;
            for (int c = 0; c < 15; ++c) row[(35 + c) ^ sw] = f2b(obs[b * 55 + 10 + 15 * oj + c]);
            for (int c = 0; c < 4; ++c)  row[(50 + c) ^ sw] = f2b(act[b * 4 + c]);
            for (int c = 54; c < 64; ++c) row[c ^ sw] = 0;
        }
    }
    __syncthreads();

    u32 s2w[4][2];    // net1 pair-sums (brief: epilogue -> post-barrier write)

    // ---- Phi networks (net 0: w1/w2, net 1: w3/w4) ----
    for (int net = 0; net < 2; ++net) {
        const u16* Wl1 = wsz + (net ? 16384 : 0);
        const u16* Wl2 = wsz + 32768 + (net ? 65536 : 0);
        const float* bl1 = net ? b3 : b1;
        const float* bl2 = net ? b4 : b2;

        // Layer 1: A=W1^T frags, B=inp rows rt=2p+wr. D=(batch=lr, hid=lg*4+reg)
        f4 acc[3][4];
        #pragma unroll
        for (int p = 0; p < 3; ++p)
            #pragma unroll
            for (int c = 0; c < 4; ++c) acc[p][c] = (f4){0.f, 0.f, 0.f, 0.f};
        __builtin_amdgcn_s_setprio(1);
        #pragma unroll 1
        for (int kt = 0; kt < 2; ++kt) {
            bf8 wfr[4];
            #pragma unroll
            for (int c = 0; c < 4; ++c)
                wfr[c] = *(const bf8*)(Wl1 + (size_t)(((kt * 16 + wc * 4 + c) * 64 + lane) * 8));
            #pragma unroll
            for (int p = 0; p < 3; ++p) {
                bf8 xfr = *(const bf8*)(&pool[((2 * p + wr) * 16 + lr) * 64 + ((kt * 32 + lg * 8) ^ swr)]);
                #pragma unroll
                for (int c = 0; c < 4; ++c)
                    acc[p][c] = __builtin_amdgcn_mfma_f32_16x16x32_bf16(wfr[c], xfr, acc[p][c], 0, 0, 0);
            }
        }
        __builtin_amdgcn_s_setprio(0);
        #pragma unroll
        for (int c = 0; c < 4; ++c) {
            float4 bv = *(const float4*)(bl1 + (wc * 4 + c) * 16 + lg * 4);
            #pragma unroll
            for (int p = 0; p < 3; ++p) {
                uint2 w;
                w.x = pk2(fmaxf(acc[p][c][0] + bv.x, 0.f), fmaxf(acc[p][c][1] + bv.y, 0.f));
                w.y = pk2(fmaxf(acc[p][c][2] + bv.z, 0.f), fmaxf(acc[p][c][3] + bv.w, 0.f));
                *(uint2*)&pool[H_OFF + ((2 * p + wr) * 16 + lr) * 256 + ((((wc * 4 + c) * 16) + lg * 4) ^ swr)] = w;
            }
        }
        __syncthreads();

        // Layer 2: A=W2^T frags, B=h rows rt=2p+wr. Relu + in-register pair-sum.
        f4 acc2[3][4];
        #pragma unroll
        for (int p = 0; p < 3; ++p)
            #pragma unroll
            for (int c = 0; c < 4; ++c) acc2[p][c] = (f4){0.f, 0.f, 0.f, 0.f};
        __builtin_amdgcn_s_setprio(1);
        #pragma unroll 1
        for (int ks = 0; ks < 8; ++ks) {
            bf8 wfr[4];
            #pragma unroll
            for (int c = 0; c < 4; ++c)
                wfr[c] = *(const bf8*)(Wl2 + (size_t)(((ks * 16 + wc * 4 + c) * 64 + lane) * 8));
            #pragma unroll
            for (int p = 0; p < 3; ++p) {
                bf8 hfr = *(const bf8*)(&pool[H_OFF + ((2 * p + wr) * 16 + lr) * 256 + ((ks * 32 + lg * 8) ^ swr)]);
                #pragma unroll
                for (int c = 0; c < 4; ++c)
                    acc2[p][c] = __builtin_amdgcn_mfma_f32_16x16x32_bf16(wfr[c], hfr, acc2[p][c], 0, 0, 0);
            }
        }
        __builtin_amdgcn_s_setprio(0);
        #pragma unroll
        for (int c = 0; c < 4; ++c) {
            float4 bv = *(const float4*)(bl2 + (wc * 4 + c) * 16 + lg * 4);
            f4 sv = (f4){0.f, 0.f, 0.f, 0.f};
            #pragma unroll
            for (int p = 0; p < 3; ++p) {
                sv[0] += fmaxf(acc2[p][c][0] + bv.x, 0.f);
                sv[1] += fmaxf(acc2[p][c][1] + bv.y, 0.f);
                sv[2] += fmaxf(acc2[p][c][2] + bv.z, 0.f);
                sv[3] += fmaxf(acc2[p][c][3] + bv.w, 0.f);
            }
            if (net == 0) {
                // S1 early-evict: write straight to the dedicated SB region
                // (disjoint from h -> no race with other waves' h reads).
                uint2 w;
                w.x = pk2(sv[0], sv[1]);
                w.y = pk2(sv[2], sv[3]);
                *(uint2*)&pool[SBO + (wr * 16 + lr) * 256 + ((((wc * 4 + c) * 16) + lg * 4) ^ swr)] = w;
            } else {
                s2w[c][0] = pk2(sv[0], sv[1]);
                s2w[c][1] = pk2(sv[2], sv[3]);
            }
        }
        __syncthreads();  // h reads done before next net overwrites h / S2 write
    }

    // ---- Write S2 into dead h rows 32..63 (all h reads completed) ----
    #pragma unroll
    for (int c = 0; c < 4; ++c) {
        int base = H_OFF + S2O + (wr * 16 + lr) * 256 + ((((wc * 4 + c) * 16) + lg * 4) ^ swr);
        *(uint2*)&pool[base] = *(uint2*)&s2w[c][0];
    }
    __syncthreads();

    // ---- Rho hidden layer: wr picks the net (wr=0: S1@SB/W5, wr=1: S2/W7) ----
    {
        const u16* Wr    = wsz + (wr ? 229376 : 163840);
        const int sbase  = wr ? (H_OFF + S2O) : SBO;
        const float* br  = wr ? b7 : b5;
        f4 racc[2][4];
        #pragma unroll
        for (int rt = 0; rt < 2; ++rt)
            #pragma unroll
            for (int c = 0; c < 4; ++c) racc[rt][c] = (f4){0.f, 0.f, 0.f, 0.f};
        __builtin_amdgcn_s_setprio(1);
        #pragma unroll 1
        for (int ks = 0; ks < 8; ++ks) {
            bf8 wf[4];
            #pragma unroll
            for (int c = 0; c < 4; ++c)
                wf[c] = *(const bf8*)(Wr + (size_t)(((ks * 16 + wc * 4 + c) * 64 + lane) * 8));
            #pragma unroll
            for (int rt = 0; rt < 2; ++rt) {
                bf8 sf = *(const bf8*)(&pool[sbase + (rt * 16 + lr) * 256 + ((ks * 32 + lg * 8) ^ swr)]);
                #pragma unroll
                for (int c = 0; c < 4; ++c)
                    racc[rt][c] = __builtin_amdgcn_mfma_f32_16x16x32_bf16(wf[c], sf, racc[rt][c], 0, 0, 0);
            }
        }
        __builtin_amdgcn_s_setprio(0);
        // Epilogue: bias+relu+pack, write immediately. RH0 -> rows 64..95
        // (virgin), RH1 -> rows 0..31 (dead h; S1 lives in SB). No overlap
        // with any concurrent reads -> NO intermediate barrier needed.
        const int rdst = wr ? 0 : RH0O;
        #pragma unroll
        for (int c = 0; c < 4; ++c) {
            float4 bv = *(const float4*)(br + (wc * 4 + c) * 16 + lg * 4);
            #pragma unroll
            for (int rt = 0; rt < 2; ++rt) {
                uint2 w;
                w.x = pk2(fmaxf(racc[rt][c][0] + bv.x, 0.f), fmaxf(racc[rt][c][1] + bv.y, 0.f));
                w.y = pk2(fmaxf(racc[rt][c][2] + bv.z, 0.f), fmaxf(racc[rt][c][3] + bv.w, 0.f));
                *(uint2*)&pool[H_OFF + rdst + (rt * 16 + lr) * 256 + ((((wc * 4 + c) * 16) + lg * 4) ^ swr)] = w;
            }
        }
        __syncthreads();
    }

    // ---- Final dots, split-K over 8 waves: q = rhoH @ w6 + b6. FP32 OUT ----
    {
        int net = lane >> 5, r = lane & 31;
        int hoff = net ? H_OFF : H_OFF + RH0O;   // net0 @ rows 64..95, net1 @ rows 0..31
        const float* wv = net ? w8 : w6;
        const int swq = (r & 7) << 3;
        float s = 0.f;
        #pragma unroll
        for (int it = 0; it < 8; ++it) {
            uint2 two = *(const uint2*)&pool[hoff + r * 256 + ((wave * 32 + it * 4) ^ swq)];
            float4 wq = *(const float4*)(wv + wave * 32 + it * 4);
            s += __uint_as_float(two.x << 16)          * wq.x;
            s += __uint_as_float(two.x & 0xffff0000u)  * wq.y;
            s += __uint_as_float(two.y << 16)          * wq.z;
            s += __uint_as_float(two.y & 0xffff0000u)  * wq.w;
        }
        ((u32*)pool)[t] = __float_as_uint(s);   // partials in dead inp region
    }
    __syncthreads();
    if (t < 64) {
        int net = t >> 5, r = t & 31;
        float qv = net ? b8[0] : b6[0];
        #pragma unroll
        for (int p = 0; p < 8; ++p)
            qv += __uint_as_float(((u32*)pool)[p * 64 + t]);
        out[net * B + wg * 32 + r] = qv;
    }
}

extern "C" void kernel_launch(void* const* d_in, const int* in_sizes, int n_in,
                              void* d_out, int out_size, void* d_ws, size_t ws_size,
                              hipStream_t stream) {
    const float* obs = (const float*)d_in[0];
    const float* ag  = (const float*)d_in[1];
    const float* g   = (const float*)d_in[2];
    const float* anc = (const float*)d_in[3];
    const float* act = (const float*)d_in[4];
    const float* w1  = (const float*)d_in[5];
    const float* b1  = (const float*)d_in[6];
    const float* w2  = (const float*)d_in[7];
    const float* b2  = (const float*)d_in[8];
    const float* w3  = (const float*)d_in[9];
    const float* b3  = (const float*)d_in[10];
    const float* w4  = (const float*)d_in[11];
    const float* b4  = (const float*)d_in[12];
    const float* w5  = (const float*)d_in[13];
    const float* b5  = (const float*)d_in[14];
    const float* w6  = (const float*)d_in[15];
    const float* b6  = (const float*)d_in[16];
    const float* w7  = (const float*)d_in[17];
    const float* b7  = (const float*)d_in[18];
    const float* w8  = (const float*)d_in[19];
    const float* b8  = (const float*)d_in[20];
    u16* ws    = (u16*)d_ws;
    float* out = (float*)d_out;
    int B = in_sizes[0] / 55;

    swz_all<<<36, 256, 0, stream>>>(w1, w3, w2, w4, w5, w7, ws);
    critic_kernel<<<(B + 31) / 32, 512, 0, stream>>>(obs, ag, g, anc, act,
                                                     b1, b2, b3, b4, b5, b7,
                                                     w6, b6, w8, b8, ws, out, B);
}

// Round 15
// 190.560 us; speedup vs baseline: 1.9791x; 1.0425x over previous
//
#include <hip/hip_runtime.h>
#include <hip/hip_bf16.h>

typedef unsigned short u16;
typedef unsigned int   u32;

using bf8 = __attribute__((ext_vector_type(8))) __bf16;
using f4  = __attribute__((ext_vector_type(4))) float;

__device__ __forceinline__ float b2f(u16 u) {
    union { u32 i; float f; } v; v.i = ((u32)u) << 16; return v.f;
}
__device__ __forceinline__ u16 f2b(float f) {
    union { float f; u32 i; } v; v.f = f;
    u32 x = v.i;
    x += 0x7fffu + ((x >> 16) & 1u);   // RNE
    return (u16)(x >> 16);
}
// Packed fp32x2 -> bf16x2 (low = first arg).
__device__ __forceinline__ u32 pk2(float lo, float hi) {
    union { __hip_bfloat162 h; u32 u; } v;
    v.h = __float22bfloat162_rn(make_float2(lo, hi));
    return v.u;
}

// ---------------------------------------------------------------------------
// Weight swizzle (verified layout — unchanged; frags used as A-operands):
// dst[((kt*16+ct)*64+lane)*8+j] = bf16(W[kt*32+(lane>>4)*8+j][ct*16+(lane&15)])
// ---------------------------------------------------------------------------
__global__ void swz_all(const float* __restrict__ w1, const float* __restrict__ w3,
                        const float* __restrict__ w2, const float* __restrict__ w4,
                        const float* __restrict__ w5, const float* __restrict__ w7,
                        u16* __restrict__ ws) {
    __shared__ u16 slab[32 * 270];
    int b = blockIdx.x, t = threadIdx.x;
    const float* src; u16* dst; int kmax, kt;
    if      (b <  2) { src = w1; dst = ws;          kmax = 54;  kt = b;      }
    else if (b <  4) { src = w3; dst = ws + 16384;  kmax = 54;  kt = b - 2;  }
    else if (b < 12) { src = w2; dst = ws + 32768;  kmax = 256; kt = b - 4;  }
    else if (b < 20) { src = w4; dst = ws + 98304;  kmax = 256; kt = b - 12; }
    else if (b < 28) { src = w5; dst = ws + 163840; kmax = 256; kt = b - 20; }
    else             { src = w7; dst = ws + 229376; kmax = 256; kt = b - 28; }

    #pragma unroll
    for (int it = 0; it < 8; ++it) {
        int flat = it * 1024 + t * 4;
        int row = flat >> 8, col = flat & 255;
        int k = kt * 32 + row;
        float4 v = make_float4(0.f, 0.f, 0.f, 0.f);
        if (k < kmax) v = *(const float4*)(src + k * 256 + col);
        u32* sp = (u32*)&slab[row * 270 + col];
        sp[0] = pk2(v.x, v.y);
        sp[1] = pk2(v.z, v.w);
    }
    __syncthreads();

    int lane = t & 63, wave = t >> 6, lr = lane & 15, kg = lane >> 4;
    #pragma unroll
    for (int i = 0; i < 4; ++i) {
        int ct = wave * 4 + i;
        u16 v[8];
        #pragma unroll
        for (int j = 0; j < 8; ++j)
            v[j] = slab[(kg * 8 + j) * 270 + ct * 16 + lr];
        uint4 o;
        o.x = (u32)v[0] | ((u32)v[1] << 16);
        o.y = (u32)v[2] | ((u32)v[3] << 16);
        o.z = (u32)v[4] | ((u32)v[5] << 16);
        o.w = (u32)v[6] | ((u32)v[7] << 16);
        *(uint4*)(dst + (size_t)(((kt * 16 + ct) * 64 + lane) * 8)) = o;
    }
}

// ---------------------------------------------------------------------------
// Fused critic, operand-swapped MFMA. 512 thr / 8 waves, 2-D wave split:
//   wr = wave>>2 : batch-lane half (rt = 2p+wr -> batch lanes wr*16+lr)
//   wc = wave&3  : 4 hidden column-tiles (ct = wc*4+c)
//
// R13 results: spill fully eliminated (WRITE 512 KB), but 108 us vs R2's
// 103.5 with 2x the LDS traffic -> LDS was never binding. Both pipes <50%,
// Occ 40% -> the kernel is bound by its serialized phase/barrier chain +
// VALU overhead. THIS round: fuse the final 256->1 dot into the rho
// epilogue. Each lane holds its 32 rho pre-activations in racc; multiply
// by w6/w8 in-register (f32, more accurate than the old bf16 round-trip),
// shfl_xor-reduce over the lg quads, write one f32 partial per
// (net,batch,wc) into the dead inp region. Deletes: RH bf16 pack, RH LDS
// round-trip, the whole 512-thread final-dot phase, and one barrier.
//
// LDS layout (u16), activation rows XOR-swizzled:
//   physical = row*stride + (logical_col ^ ((row&7)<<3))
//   inp: rows 0..95, stride 64  ([0, 6144))   (dead by rho -> f32 scratch)
//   h  : rows 0..95, stride 256 ([6144, 6144+24576)); S2 -> rows 32..63
//   SB : rows 0..31, stride 256 ([30720, 38912))  <- S1 early-evict region
// Total 77824 B -> 2 blocks/CU, 4 waves/SIMD.
// ---------------------------------------------------------------------------
#define H_OFF 6144
#define S2O   (32 * 256)
#define SBO   (H_OFF + 96 * 256)

__global__ __launch_bounds__(512) __attribute__((amdgpu_waves_per_eu(4, 4)))
void critic_kernel(
    const float* __restrict__ obs, const float* __restrict__ ag,
    const float* __restrict__ g,   const float* __restrict__ anchor,
    const float* __restrict__ act,
    const float* __restrict__ b1,  const float* __restrict__ b2,
    const float* __restrict__ b3,  const float* __restrict__ b4,
    const float* __restrict__ b5,  const float* __restrict__ b7,
    const float* __restrict__ w6,  const float* __restrict__ b6,
    const float* __restrict__ w8,  const float* __restrict__ b8,
    const u16* __restrict__ wsz, float* __restrict__ out, int B) {

    __shared__ u16 pool[SBO + 32 * 256];   // 38912 u16 = 77824 B

    const int t    = threadIdx.x;
    const int lane = t & 63;
    const int wave = t >> 6;     // 0..7
    const int wr   = wave >> 2;  // 0,1 : batch-lane half / rho net
    const int wc   = wave & 3;   // 0..3: 4 column-tiles
    const int lr   = lane & 15;
    const int lg   = lane >> 4;
    const int wg   = blockIdx.x;
    const int swr  = (lr & 7) << 3;   // row-XOR swizzle (h/inp rows are ..*16+lr)

    // ---- Gather: build pair inputs (96 rows x 54, pad to 64), swizzled.
    // 2 threads/row: part 0 -> cols [0,32), part 1 -> cols [32,64).
    if (t < 192) {
        const int O1[3] = {0, 0, 1}, O2[3] = {1, 2, 2};
        const int JA[3] = {3, 4, 6}, KA[3] = {5, 7, 8};
        int rr = t >> 1, part = t & 1;
        int p = rr >> 5, bl = rr & 31;
        int b = wg * 32 + bl;
        int j = JA[p], k = KA[p];
        bool sel = (anchor[b * 9 + j] - anchor[b * 9 + k]) >= 0.0f;
        u16* row = &pool[rr * 64];
        const int sw = (rr & 7) << 3;
        const u16 ONE = 0x3F80;
        if (part == 0) {
            int bit2 = sel ? j : k;
            int oi = sel ? O1[p] : O2[p];
            row[0 ^ sw] = f2b(ag[b * 9 + p]);
            row[1 ^ sw] = f2b(ag[b * 9 + bit2]);
            row[2 ^ sw] = f2b(g[b * 9 + p]);
            row[3 ^ sw] = f2b(g[b * 9 + bit2]);
            for (int c = 0; c < 10; ++c) row[(4 + c) ^ sw] = f2b(obs[b * 55 + c]);
            row[14 ^ sw] = (oi == 0) ? ONE : 0;
            row[15 ^ sw] = (oi == 1) ? ONE : 0;
            row[16 ^ sw] = (oi == 2) ? ONE : 0;
            for (int c = 0; c < 15; ++c) row[(17 + c) ^ sw] = f2b(obs[b * 55 + 10 + 15 * oi + c]);
        } else {
            int oj = sel ? O2[p] : O1[p];
            row[32 ^ sw] = (oj == 0) ? ONE : 0;
            row[33 ^ sw] = (oj == 1) ? ONE : 0;
            row[34 ^ sw] = (oj == 2) ? ONE : 0;
            for (int c = 0; c < 15; ++c) row[(35 + c) ^ sw] = f2b(obs[b * 55 + 10 + 15 * oj + c]);
            for (int c = 0; c < 4; ++c)  row[(50 + c) ^ sw] = f2b(act[b * 4 + c]);
            for (int c = 54; c < 64; ++c) row[c ^ sw] = 0;
        }
    }
    __syncthreads();

    u32 s2w[4][2];    // net1 pair-sums (brief: epilogue -> post-barrier write)

    // ---- Phi networks (net 0: w1/w2, net 1: w3/w4) ----
    for (int net = 0; net < 2; ++net) {
        const u16* Wl1 = wsz + (net ? 16384 : 0);
        const u16* Wl2 = wsz + 32768 + (net ? 65536 : 0);
        const float* bl1 = net ? b3 : b1;
        const float* bl2 = net ? b4 : b2;

        // Layer 1: A=W1^T frags, B=inp rows rt=2p+wr. D=(batch=lr, hid=lg*4+reg)
        f4 acc[3][4];
        #pragma unroll
        for (int p = 0; p < 3; ++p)
            #pragma unroll
            for (int c = 0; c < 4; ++c) acc[p][c] = (f4){0.f, 0.f, 0.f, 0.f};
        __builtin_amdgcn_s_setprio(1);
        #pragma unroll 1
        for (int kt = 0; kt < 2; ++kt) {
            bf8 wfr[4];
            #pragma unroll
            for (int c = 0; c < 4; ++c)
                wfr[c] = *(const bf8*)(Wl1 + (size_t)(((kt * 16 + wc * 4 + c) * 64 + lane) * 8));
            #pragma unroll
            for (int p = 0; p < 3; ++p) {
                bf8 xfr = *(const bf8*)(&pool[((2 * p + wr) * 16 + lr) * 64 + ((kt * 32 + lg * 8) ^ swr)]);
                #pragma unroll
                for (int c = 0; c < 4; ++c)
                    acc[p][c] = __builtin_amdgcn_mfma_f32_16x16x32_bf16(wfr[c], xfr, acc[p][c], 0, 0, 0);
            }
        }
        __builtin_amdgcn_s_setprio(0);
        #pragma unroll
        for (int c = 0; c < 4; ++c) {
            float4 bv = *(const float4*)(bl1 + (wc * 4 + c) * 16 + lg * 4);
            #pragma unroll
            for (int p = 0; p < 3; ++p) {
                uint2 w;
                w.x = pk2(fmaxf(acc[p][c][0] + bv.x, 0.f), fmaxf(acc[p][c][1] + bv.y, 0.f));
                w.y = pk2(fmaxf(acc[p][c][2] + bv.z, 0.f), fmaxf(acc[p][c][3] + bv.w, 0.f));
                *(uint2*)&pool[H_OFF + ((2 * p + wr) * 16 + lr) * 256 + ((((wc * 4 + c) * 16) + lg * 4) ^ swr)] = w;
            }
        }
        __syncthreads();

        // Layer 2: A=W2^T frags, B=h rows rt=2p+wr. Relu + in-register pair-sum.
        f4 acc2[3][4];
        #pragma unroll
        for (int p = 0; p < 3; ++p)
            #pragma unroll
            for (int c = 0; c < 4; ++c) acc2[p][c] = (f4){0.f, 0.f, 0.f, 0.f};
        __builtin_amdgcn_s_setprio(1);
        #pragma unroll 1
        for (int ks = 0; ks < 8; ++ks) {
            bf8 wfr[4];
            #pragma unroll
            for (int c = 0; c < 4; ++c)
                wfr[c] = *(const bf8*)(Wl2 + (size_t)(((ks * 16 + wc * 4 + c) * 64 + lane) * 8));
            #pragma unroll
            for (int p = 0; p < 3; ++p) {
                bf8 hfr = *(const bf8*)(&pool[H_OFF + ((2 * p + wr) * 16 + lr) * 256 + ((ks * 32 + lg * 8) ^ swr)]);
                #pragma unroll
                for (int c = 0; c < 4; ++c)
                    acc2[p][c] = __builtin_amdgcn_mfma_f32_16x16x32_bf16(wfr[c], hfr, acc2[p][c], 0, 0, 0);
            }
        }
        __builtin_amdgcn_s_setprio(0);
        #pragma unroll
        for (int c = 0; c < 4; ++c) {
            float4 bv = *(const float4*)(bl2 + (wc * 4 + c) * 16 + lg * 4);
            f4 sv = (f4){0.f, 0.f, 0.f, 0.f};
            #pragma unroll
            for (int p = 0; p < 3; ++p) {
                sv[0] += fmaxf(acc2[p][c][0] + bv.x, 0.f);
                sv[1] += fmaxf(acc2[p][c][1] + bv.y, 0.f);
                sv[2] += fmaxf(acc2[p][c][2] + bv.z, 0.f);
                sv[3] += fmaxf(acc2[p][c][3] + bv.w, 0.f);
            }
            if (net == 0) {
                // S1 early-evict: write straight to the dedicated SB region
                // (disjoint from h -> no race with other waves' h reads).
                uint2 w;
                w.x = pk2(sv[0], sv[1]);
                w.y = pk2(sv[2], sv[3]);
                *(uint2*)&pool[SBO + (wr * 16 + lr) * 256 + ((((wc * 4 + c) * 16) + lg * 4) ^ swr)] = w;
            } else {
                s2w[c][0] = pk2(sv[0], sv[1]);
                s2w[c][1] = pk2(sv[2], sv[3]);
            }
        }
        __syncthreads();  // h reads done before next net overwrites h / S2 write
    }

    // ---- Write S2 into dead h rows 32..63 (all h reads completed) ----
    #pragma unroll
    for (int c = 0; c < 4; ++c) {
        int base = H_OFF + S2O + (wr * 16 + lr) * 256 + ((((wc * 4 + c) * 16) + lg * 4) ^ swr);
        *(uint2*)&pool[base] = *(uint2*)&s2w[c][0];
    }
    __syncthreads();

    // ---- Rho hidden layer + FUSED final dot ----
    // wr picks the net (wr=0: S1@SB/W5/b5/w6, wr=1: S2/W7/b7/w8).
    {
        const u16* Wr    = wsz + (wr ? 229376 : 163840);
        const int sbase  = wr ? (H_OFF + S2O) : SBO;
        const float* br  = wr ? b7 : b5;
        const float* wq  = wr ? w8 : w6;
        f4 racc[2][4];
        #pragma unroll
        for (int rt = 0; rt < 2; ++rt)
            #pragma unroll
            for (int c = 0; c < 4; ++c) racc[rt][c] = (f4){0.f, 0.f, 0.f, 0.f};
        __builtin_amdgcn_s_setprio(1);
        #pragma unroll 1
        for (int ks = 0; ks < 8; ++ks) {
            bf8 wf[4];
            #pragma unroll
            for (int c = 0; c < 4; ++c)
                wf[c] = *(const bf8*)(Wr + (size_t)(((ks * 16 + wc * 4 + c) * 64 + lane) * 8));
            #pragma unroll
            for (int rt = 0; rt < 2; ++rt) {
                bf8 sf = *(const bf8*)(&pool[sbase + (rt * 16 + lr) * 256 + ((ks * 32 + lg * 8) ^ swr)]);
                #pragma unroll
                for (int c = 0; c < 4; ++c)
                    racc[rt][c] = __builtin_amdgcn_mfma_f32_16x16x32_bf16(wf[c], sf, racc[rt][c], 0, 0, 0);
            }
        }
        __builtin_amdgcn_s_setprio(0);
        // Fused epilogue: q-partial = sum_h relu(racc + b) * wq[h], f32.
        // Lane holds hidden units (wc*4+c)*16+lg*4+i for batch rt*16+lr.
        float part[2] = {0.f, 0.f};
        #pragma unroll
        for (int c = 0; c < 4; ++c) {
            float4 bv = *(const float4*)(br + (wc * 4 + c) * 16 + lg * 4);
            float4 wv = *(const float4*)(wq + (wc * 4 + c) * 16 + lg * 4);
            #pragma unroll
            for (int rt = 0; rt < 2; ++rt) {
                part[rt] += fmaxf(racc[rt][c][0] + bv.x, 0.f) * wv.x
                          + fmaxf(racc[rt][c][1] + bv.y, 0.f) * wv.y
                          + fmaxf(racc[rt][c][2] + bv.z, 0.f) * wv.z
                          + fmaxf(racc[rt][c][3] + bv.w, 0.f) * wv.w;
            }
        }
        // Reduce over the 4 lg quads (lane bits 4,5); all lanes same-lr equal.
        #pragma unroll
        for (int rt = 0; rt < 2; ++rt) {
            part[rt] += __shfl_xor(part[rt], 16);
            part[rt] += __shfl_xor(part[rt], 32);
        }
        // One f32 partial per (net, batch, wc) into the dead inp region.
        if (lane < 16) {
            float* fs = (float*)pool;
            fs[(wr * 32 + lane) * 4 + wc]      = part[0];
            fs[(wr * 32 + 16 + lane) * 4 + wc] = part[1];
        }
        __syncthreads();
    }

    // ---- Final reduce: 64 threads sum the 4 wc partials. FP32 OUT ----
    if (t < 64) {
        int net = t >> 5, b = t & 31;
        const float* fs = (const float*)pool;
        float qv = net ? b8[0] : b6[0];
        #pragma unroll
        for (int p = 0; p < 4; ++p)
            qv += fs[(net * 32 + b) * 4 + p];
        out[net * B + wg * 32 + b] = qv;
    }
}

extern "C" void kernel_launch(void* const* d_in, const int* in_sizes, int n_in,
                              void* d_out, int out_size, void* d_ws, size_t ws_size,
                              hipStream_t stream) {
    const float* obs = (const float*)d_in[0];
    const float* ag  = (const float*)d_in[1];
    const float* g   = (const float*)d_in[2];
    const float* anc = (const float*)d_in[3];
    const float* act = (const float*)d_in[4];
    const float* w1  = (const float*)d_in[5];
    const float* b1  = (const float*)d_in[6];
    const float* w2  = (const float*)d_in[7];
    const float* b2  = (const float*)d_in[8];
    const float* w3  = (const float*)d_in[9];
    const float* b3  = (const float*)d_in[10];
    const float* w4  = (const float*)d_in[11];
    const float* b4  = (const float*)d_in[12];
    const float* w5  = (const float*)d_in[13];
    const float* b5  = (const float*)d_in[14];
    const float* w6  = (const float*)d_in[15];
    const float* b6  = (const float*)d_in[16];
    const float* w7  = (const float*)d_in[17];
    const float* b7  = (const float*)d_in[18];
    const float* w8  = (const float*)d_in[19];
    const float* b8  = (const float*)d_in[20];
    u16* ws    = (u16*)d_ws;
    float* out = (float*)d_out;
    int B = in_sizes[0] / 55;

    swz_all<<<36, 256, 0, stream>>>(w1, w3, w2, w4, w5, w7, ws);
    critic_kernel<<<(B + 31) / 32, 512, 0, stream>>>(obs, ag, g, anc, act,
                                                     b1, b2, b3, b4, b5, b7,
                                                     w6, b6, w8, b8, ws, out, B);
}